// Round 3
// baseline (47586.188 us; speedup 1.0000x reference)
//
#include <hip/hip_runtime.h>
#include <hip/hip_bf16.h>
#include <math.h>

#define B 64
#define T 160
#define P 196
#define ENC 2048
#define ATT 512
#define EMB 512
#define HID 1024
#define KTOT 3584   // EMB + ENC + HID
#define PAD_TOK 3

__device__ __forceinline__ float sigm(float x){ return 1.0f/(1.0f+__expf(-x)); }
__device__ __forceinline__ float dot4(float4 a, float4 b){ return a.x*b.x + a.y*b.y + a.z*b.z + a.w*b.w; }
__device__ __forceinline__ float bf_lo(unsigned v){ return __uint_as_float(v << 16); }
__device__ __forceinline__ float bf_hi(unsigned v){ return __uint_as_float(v & 0xFFFF0000u); }

// ---------- sort: stable descending by lens (replicates argsort(-lens)) ----------
__global__ void k_sort(const int* lens, int* idx, int* rank){
    __shared__ int L[B];
    int i = threadIdx.x;
    L[i] = lens[i];
    __syncthreads();
    int li = L[i];
    int r = 0;
    for (int j = 0; j < B; ++j){
        int lj = L[j];
        if (lj > li || (lj == li && j < i)) r++;
    }
    rank[i] = r;   // sorted position of original i
    idx[r] = i;    // original index at sorted position r
}

// ---------- init h0/c0 (sorted order) ----------
__global__ void k_init_hc(const float* enc_h, const float* enc_c, const int* idx, float* h, float* c){
    int j = blockIdx.x;
    int o = idx[j];
    for (int k = threadIdx.x; k < HID; k += blockDim.x){
        float hv = (k < 512) ? enc_h[o*512 + k] : enc_h[B*512 + o*512 + (k-512)];
        float cv = (k < 512) ? enc_c[o*512 + k] : enc_c[B*512 + o*512 + (k-512)];
        h[j*HID + k] = hv;
        c[j*HID + k] = cv;
    }
}

// ---------- att1[j,p,a] = img[idx[j],p,:]·Wea[a,:] + bea[a]  (M=B*P, N=ATT, K=ENC), bf16 out ----------
#define A1_KC 32
__global__ __launch_bounds__(256) void k_att1(const float* img, const float* Wea, const float* bea,
                                              const int* idx, __hip_bfloat16* att1w){
    __shared__ __align__(16) float As[64][A1_KC+1];
    __shared__ __align__(16) float Bs[128][A1_KC+1];
    int m0 = blockIdx.x * 64;
    int n0 = blockIdx.y * 128;
    int tid = threadIdx.x;
    int tx = tid & 15, ty = tid >> 4;
    float acc[4][8];
    #pragma unroll
    for (int mi=0;mi<4;mi++)
        #pragma unroll
        for (int ni=0;ni<8;ni++) acc[mi][ni]=0.f;

    for (int kc = 0; kc < ENC/A1_KC; ++kc){
        int k0 = kc*A1_KC;
        // stage A: 64 rows x 32 floats = 512 f4
        for (int f = tid; f < 512; f += 256){
            int row = f >> 3, c4 = f & 7;
            int g = m0 + row;
            int j = g / P, p = g - j*P;
            int o = idx[j];
            float4 v = *(const float4*)(img + ((size_t)(o*P + p))*ENC + k0 + c4*4);
            As[row][c4*4+0]=v.x; As[row][c4*4+1]=v.y; As[row][c4*4+2]=v.z; As[row][c4*4+3]=v.w;
        }
        // stage B: 128 rows x 32 floats = 1024 f4
        for (int f = tid; f < 1024; f += 256){
            int row = f >> 3, c4 = f & 7;
            float4 v = *(const float4*)(Wea + (size_t)(n0 + row)*ENC + k0 + c4*4);
            Bs[row][c4*4+0]=v.x; Bs[row][c4*4+1]=v.y; Bs[row][c4*4+2]=v.z; Bs[row][c4*4+3]=v.w;
        }
        __syncthreads();
        #pragma unroll 4
        for (int k = 0; k < A1_KC; ++k){
            float a[4], b[8];
            #pragma unroll
            for (int mi=0;mi<4;mi++) a[mi] = As[ty + 16*mi][k];
            #pragma unroll
            for (int ni=0;ni<8;ni++) b[ni] = Bs[tx + 16*ni][k];
            #pragma unroll
            for (int mi=0;mi<4;mi++)
                #pragma unroll
                for (int ni=0;ni<8;ni++) acc[mi][ni] += a[mi]*b[ni];
        }
        __syncthreads();
    }
    #pragma unroll
    for (int mi=0;mi<4;mi++){
        int g = m0 + ty + 16*mi;
        #pragma unroll
        for (int ni=0;ni<8;ni++){
            int n = n0 + tx + 16*ni;
            att1w[(size_t)g*ATT + n] = __float2bfloat16(acc[mi][ni] + bea[n]);
        }
    }
}

// ---------- per-step: att2 + e + softmax -> alpha ----------
__global__ __launch_bounds__(256) void k_step_att(const float* hIn, const __hip_bfloat16* att1w,
        const float* Wda, const float* bda, const float* wfa, const float* bfa,
        const int* idx, const int* rank, const int* lens,
        float* alphaWs, float* outA, int t){
    int j = blockIdx.x, tid = threadIdx.x;
    __shared__ __align__(16) float hL[HID];
    __shared__ float att2L[ATT];
    __shared__ float wfaL[ATT];
    __shared__ float red[256];
    int o = idx[j];
    int w = rank[j];
    int lj = lens[o];

    ((float4*)hL)[tid] = ((const float4*)(hIn + j*HID))[tid];   // 256 f4 = 1024 floats
    wfaL[tid] = wfa[tid];
    wfaL[tid+256] = wfa[tid+256];
    __syncthreads();

    #pragma unroll
    for (int rep = 0; rep < 2; ++rep){
        int a = tid + rep*256;
        float acc = bda[a];
        const float4* wr = (const float4*)(Wda + (size_t)a*HID);
        #pragma unroll 4
        for (int k4 = 0; k4 < HID/4; ++k4){
            acc += dot4(wr[k4], ((float4*)hL)[k4]);
        }
        att2L[a] = acc;
    }
    __syncthreads();

    float e = -1e30f;
    if (tid < P){
        const unsigned* ar = (const unsigned*)(att1w + ((size_t)(j*P + tid))*ATT);
        float acc = 0.f;
        #pragma unroll 4
        for (int q = 0; q < ATT/2; ++q){
            unsigned v = ar[q];
            float x0 = bf_lo(v);
            float x1 = bf_hi(v);
            float r0 = fmaxf(x0 + att2L[2*q+0], 0.f);
            float r1 = fmaxf(x1 + att2L[2*q+1], 0.f);
            acc += r0*wfaL[2*q+0] + r1*wfaL[2*q+1];
        }
        e = acc + bfa[0];
    }
    // softmax over p (196)
    red[tid] = (tid < P) ? e : -1e30f;
    __syncthreads();
    for (int s = 128; s > 0; s >>= 1){
        if (tid < s) red[tid] = fmaxf(red[tid], red[tid+s]);
        __syncthreads();
    }
    float m = red[0];
    __syncthreads();
    float ex = (tid < P) ? __expf(e - m) : 0.f;
    red[tid] = ex;
    __syncthreads();
    for (int s = 128; s > 0; s >>= 1){
        if (tid < s) red[tid] += red[tid+s];
        __syncthreads();
    }
    float ssum = red[0];
    if (tid < P){
        float alpha = ex / ssum;
        alphaWs[j*P + tid] = alpha;   // unmasked, for context
        outA[((size_t)(w*T + t))*P + tid] = (t < lj) ? alpha : 0.f;
    }
}

// ---------- per-step: context + gate -> gc ----------
__global__ __launch_bounds__(256) void k_step_ctx(const float* hIn, const float* img,
        const float* Wfb, const float* bfb, const float* alphaWs, const int* idx, float* gc){
    int j = blockIdx.x, ec = blockIdx.y, tid = threadIdx.x;
    __shared__ float aL[P];
    __shared__ __align__(16) float hL[HID];
    int o = idx[j];
    if (tid < P) aL[tid] = alphaWs[j*P + tid];
    ((float4*)hL)[tid] = ((const float4*)(hIn + j*HID))[tid];
    __syncthreads();

    int e = ec*256 + tid;
    const float* ib = img + (size_t)o*P*ENC + e;
    float ctx = 0.f;
    #pragma unroll 4
    for (int p = 0; p < P; ++p) ctx += aL[p] * ib[(size_t)p*ENC];

    float acc = bfb[e];
    const float4* wr = (const float4*)(Wfb + (size_t)e*HID);
    #pragma unroll 4
    for (int k4 = 0; k4 < HID/4; ++k4){
        acc += dot4(wr[k4], ((float4*)hL)[k4]);
    }
    gc[j*ENC + e] = sigm(acc) * ctx;
}

// ---------- per-step: gates GEMM + LSTM pointwise + masked state update + output ----------
#define GKC 128
__global__ __launch_bounds__(256) void k_step_gates(const float* hIn, float* hOut, float* c,
        const float* gc, const float* emb, const int* sent,
        const float* Wih, const float* bih, const float* Whh, const float* bhh,
        const int* idx, const int* rank, const int* lens,
        float* outH, int t){
    __shared__ __align__(16) float actL[64][GKC+4];
    __shared__ float gatesL[16][65];
    __shared__ int tokL[64], lensL[64], wLs[64];
    int tid = threadIdx.x;
    int u0 = blockIdx.x * 4;

    if (tid < 64){
        int o = idx[tid];
        tokL[tid] = sent[o*T + t];
        lensL[tid] = lens[o];
        wLs[tid] = rank[tid];
    }
    __syncthreads();

    int tj = tid & 31, tr = tid >> 5;           // tj in [0,32), tr in [0,8)
    int gi = tr & 3;
    int du0 = tr >> 2;                          // row lr=tr   -> du0 in {0,1}
    int du1 = du0 + 2;                          // row lr=tr+8 -> du1 in {2,3}
    int R0 = gi*HID + u0 + du0;
    int R1 = gi*HID + u0 + du1;
    float acc00=0.f, acc01=0.f, acc10=0.f, acc11=0.f;

    int row = tid >> 2;
    int c0f = (tid & 3) * 32;

    for (int kc = 0; kc < KTOT/GKC; ++kc){
        int k0 = kc * GKC;
        // stage activations [x_t | gc | h]
        const float* src;
        if (k0 < EMB){
            int tok = tokL[row];
            src = emb + (size_t)tok*EMB + k0;        // emb[PAD] is zero by construction
        } else if (k0 < EMB+ENC){
            src = gc + (size_t)row*ENC + (k0 - EMB);
        } else {
            src = hIn + (size_t)row*HID + (k0 - EMB - ENC);
        }
        {
            const float4* s4 = (const float4*)(src + c0f);
            float4* d4 = (float4*)(&actL[row][c0f]);
            #pragma unroll
            for (int ii = 0; ii < 8; ++ii) d4[ii] = s4[ii];
        }
        __syncthreads();
        // compute
        const float4 *w0, *w1;
        if (k0 < EMB+ENC){
            w0 = (const float4*)(Wih + (size_t)R0*(EMB+ENC) + k0);
            w1 = (const float4*)(Wih + (size_t)R1*(EMB+ENC) + k0);
        } else {
            w0 = (const float4*)(Whh + (size_t)R0*HID + (k0 - EMB - ENC));
            w1 = (const float4*)(Whh + (size_t)R1*HID + (k0 - EMB - ENC));
        }
        #pragma unroll 8
        for (int k4 = 0; k4 < GKC/4; ++k4){
            float4 wv0 = w0[k4];
            float4 wv1 = w1[k4];
            float4 a0 = *(const float4*)(&actL[tj][k4*4]);
            float4 a1 = *(const float4*)(&actL[tj+32][k4*4]);
            acc00 += dot4(a0, wv0);
            acc01 += dot4(a0, wv1);
            acc10 += dot4(a1, wv0);
            acc11 += dot4(a1, wv1);
        }
        __syncthreads();
    }

    float b0 = bih[R0] + bhh[R0];
    float b1 = bih[R1] + bhh[R1];
    gatesL[tr  ][tj   ] = acc00 + b0;
    gatesL[tr+8][tj   ] = acc01 + b1;
    gatesL[tr  ][tj+32] = acc10 + b0;
    gatesL[tr+8][tj+32] = acc11 + b1;
    __syncthreads();

    // pointwise: one thread per (j, u)
    int j = tid >> 2, du = tid & 3;
    int u = u0 + du;
    float iv = gatesL[du*4+0][j];
    float fv = gatesL[du*4+1][j];
    float gv = gatesL[du*4+2][j];
    float ov = gatesL[du*4+3][j];
    float ig = sigm(iv), fg = sigm(fv), gg = tanhf(gv), og = sigm(ov);
    float cOld = c[j*HID + u];
    float cNew = fg*cOld + ig*gg;
    float hNew = og*tanhf(cNew);
    bool active = (t < lensL[j]);
    float hOld = hIn[j*HID + u];
    hOut[j*HID + u] = active ? hNew : hOld;
    c[j*HID + u]    = active ? cNew : cOld;
    outH[((size_t)(wLs[j]*T + t))*HID + u] = active ? hNew : 0.f;
}

extern "C" void kernel_launch(void* const* d_in, const int* in_sizes, int n_in,
                              void* d_out, int out_size, void* d_ws, size_t ws_size,
                              hipStream_t stream) {
    const float* img   = (const float*)d_in[0];
    const int*   sent  = (const int*)  d_in[1];
    const float* enc_h = (const float*)d_in[2];
    const float* enc_c = (const float*)d_in[3];
    const int*   lens  = (const int*)  d_in[4];
    const float* emb   = (const float*)d_in[5];
    const float* Wea   = (const float*)d_in[6];
    const float* bea   = (const float*)d_in[7];
    const float* Wda   = (const float*)d_in[8];
    const float* bda   = (const float*)d_in[9];
    const float* wfa   = (const float*)d_in[10];
    const float* bfa   = (const float*)d_in[11];
    const float* Wfb   = (const float*)d_in[12];
    const float* bfb   = (const float*)d_in[13];
    const float* Wih   = (const float*)d_in[14];
    const float* bih   = (const float*)d_in[15];
    const float* Whh   = (const float*)d_in[16];
    const float* bhh   = (const float*)d_in[17];

    float* outH = (float*)d_out;                       // [B,T,HID] float32
    float* outA = outH + (size_t)B*T*HID;              // [B,T,P]  float32

    char* wsb = (char*)d_ws;
    int* idxW  = (int*)wsb;
    int* rankW = idxW + 64;
    __hip_bfloat16* att1w = (__hip_bfloat16*)(wsb + 512);            // B*P*ATT bf16 = 12.85MB
    float* f = (float*)(wsb + 512 + (size_t)B*P*ATT*2);
    float* hA     = f;
    float* hB     = hA + B*HID;
    float* cW     = hB + B*HID;
    float* alphaW = cW + B*HID;
    float* gcW    = alphaW + B*P;

    k_sort<<<1, 64, 0, stream>>>(lens, idxW, rankW);
    k_init_hc<<<B, 256, 0, stream>>>(enc_h, enc_c, idxW, hA, cW);
    k_att1<<<dim3((B*P)/64, ATT/128), 256, 0, stream>>>(img, Wea, bea, idxW, att1w);

    for (int t = 0; t < T; ++t){
        const float* hIn = (t & 1) ? hB : hA;
        float*       hOut = (t & 1) ? hA : hB;
        k_step_att<<<B, 256, 0, stream>>>(hIn, att1w, Wda, bda, wfa, bfa,
                                          idxW, rankW, lens, alphaW, outA, t);
        k_step_ctx<<<dim3(B, ENC/256), 256, 0, stream>>>(hIn, img, Wfb, bfb, alphaW, idxW, gcW);
        k_step_gates<<<HID/4, 256, 0, stream>>>(hIn, hOut, cW, gcW, emb, sent,
                                                Wih, bih, Whh, bhh,
                                                idxW, rankW, lens, outH, t);
    }
}

// Round 4
// 28703.946 us; speedup vs baseline: 1.6578x; 1.6578x over previous
//
#include <hip/hip_runtime.h>
#include <hip/hip_bf16.h>
#include <math.h>

#define B 64
#define T 160
#define P 196
#define ENC 2048
#define ATT 512
#define EMB 512
#define HID 1024
#define KTOT 3584   // EMB + ENC + HID
#define N2 2560     // ATT + ENC

typedef __attribute__((ext_vector_type(8))) short bf16x8;
typedef __attribute__((ext_vector_type(4))) float f32x4;

__device__ __forceinline__ float sigm(float x){ return 1.0f/(1.0f+__expf(-x)); }
__device__ __forceinline__ float bf_lo(unsigned v){ return __uint_as_float(v << 16); }
__device__ __forceinline__ float bf_hi(unsigned v){ return __uint_as_float(v & 0xFFFF0000u); }

// ---------- sort: stable descending by lens ----------
__global__ void k_sort(const int* lens, int* idx, int* rank){
    __shared__ int L[B];
    int i = threadIdx.x;
    L[i] = lens[i];
    __syncthreads();
    int li = L[i];
    int r = 0;
    for (int j = 0; j < B; ++j){
        int lj = L[j];
        if (lj > li || (lj == li && j < i)) r++;
    }
    rank[i] = r;
    idx[r] = i;
}

// ---------- init h0/c0 (sorted order) + bf16 copy ----------
__global__ void k_init_hc(const float* enc_h, const float* enc_c, const int* idx,
                          float* h, float* c, __hip_bfloat16* h_bf){
    int j = blockIdx.x;
    int o = idx[j];
    for (int k = threadIdx.x; k < HID; k += blockDim.x){
        float hv = (k < 512) ? enc_h[o*512 + k] : enc_h[B*512 + o*512 + (k-512)];
        float cv = (k < 512) ? enc_c[o*512 + k] : enc_c[B*512 + o*512 + (k-512)];
        h[j*HID + k] = hv;
        c[j*HID + k] = cv;
        h_bf[j*HID + k] = __float2bfloat16(hv);
    }
}

// ---------- weight conversions (once) ----------
__global__ void k_cvt_gates_w(const float* Wih, const float* Whh, const float* bih, const float* bhh,
                              __hip_bfloat16* Wcat, float* bsum){
    int n = blockIdx.x;              // 0..4095, n = 4u+g
    int u = n >> 2, g = n & 3;
    int r = g*HID + u;
    const float* s1 = Wih + (size_t)r*(EMB+ENC);
    const float* s2 = Whh + (size_t)r*HID;
    __hip_bfloat16* dst = Wcat + (size_t)n*KTOT;
    for (int k = threadIdx.x; k < EMB+ENC; k += 256) dst[k] = __float2bfloat16(s1[k]);
    for (int k = threadIdx.x; k < HID; k += 256) dst[EMB+ENC+k] = __float2bfloat16(s2[k]);
    if (threadIdx.x == 0) bsum[n] = bih[r] + bhh[r];
}

__global__ void k_cvt_w2(const float* Wda, const float* bda, const float* Wfb, const float* bfb,
                         __hip_bfloat16* W2, float* bias2){
    int n = blockIdx.x;              // 0..2559
    const float* src = (n < ATT) ? (Wda + (size_t)n*HID) : (Wfb + (size_t)(n-ATT)*HID);
    __hip_bfloat16* dst = W2 + (size_t)n*HID;
    for (int k = threadIdx.x; k < HID; k += 256) dst[k] = __float2bfloat16(src[k]);
    if (threadIdx.x == 0) bias2[n] = (n < ATT) ? bda[n] : bfb[n-ATT];
}

__global__ void k_cvt_emb(const float* emb, __hip_bfloat16* emb_bf){
    size_t i = (size_t)blockIdx.x*256 + threadIdx.x;   // grid 20000 -> 5,120,000
    emb_bf[i] = __float2bfloat16(emb[i]);
}

__global__ void k_cvt_img(const float* img, const int* idx, __hip_bfloat16* img_s){
    int j = blockIdx.y;
    int o = idx[j];
    size_t off = (size_t)blockIdx.x*256 + threadIdx.x;   // grid.x = 1568 -> P*ENC = 401408
    img_s[(size_t)j*P*ENC + off] = __float2bfloat16(img[(size_t)o*P*ENC + off]);
}

// ---------- att1 (once): img fp32 -> att1w bf16 ----------
#define A1_KC 32
__global__ __launch_bounds__(256) void k_att1(const float* img, const float* Wea, const float* bea,
                                              const int* idx, __hip_bfloat16* att1w){
    __shared__ __align__(16) float As[64][A1_KC+1];
    __shared__ __align__(16) float Bs[128][A1_KC+1];
    int m0 = blockIdx.x * 64;
    int n0 = blockIdx.y * 128;
    int tid = threadIdx.x;
    int tx = tid & 15, ty = tid >> 4;
    float acc[4][8];
    #pragma unroll
    for (int mi=0;mi<4;mi++)
        #pragma unroll
        for (int ni=0;ni<8;ni++) acc[mi][ni]=0.f;

    for (int kc = 0; kc < ENC/A1_KC; ++kc){
        int k0 = kc*A1_KC;
        for (int f = tid; f < 512; f += 256){
            int row = f >> 3, c4 = f & 7;
            int g = m0 + row;
            int j = g / P, p = g - j*P;
            int o = idx[j];
            float4 v = *(const float4*)(img + ((size_t)(o*P + p))*ENC + k0 + c4*4);
            As[row][c4*4+0]=v.x; As[row][c4*4+1]=v.y; As[row][c4*4+2]=v.z; As[row][c4*4+3]=v.w;
        }
        for (int f = tid; f < 1024; f += 256){
            int row = f >> 3, c4 = f & 7;
            float4 v = *(const float4*)(Wea + (size_t)(n0 + row)*ENC + k0 + c4*4);
            Bs[row][c4*4+0]=v.x; Bs[row][c4*4+1]=v.y; Bs[row][c4*4+2]=v.z; Bs[row][c4*4+3]=v.w;
        }
        __syncthreads();
        #pragma unroll 4
        for (int k = 0; k < A1_KC; ++k){
            float a[4], b[8];
            #pragma unroll
            for (int mi=0;mi<4;mi++) a[mi] = As[ty + 16*mi][k];
            #pragma unroll
            for (int ni=0;ni<8;ni++) b[ni] = Bs[tx + 16*ni][k];
            #pragma unroll
            for (int mi=0;mi<4;mi++)
                #pragma unroll
                for (int ni=0;ni<8;ni++) acc[mi][ni] += a[mi]*b[ni];
        }
        __syncthreads();
    }
    #pragma unroll
    for (int mi=0;mi<4;mi++){
        int g = m0 + ty + 16*mi;
        #pragma unroll
        for (int ni=0;ni<8;ni++){
            int n = n0 + tx + 16*ni;
            att1w[(size_t)g*ATT + n] = __float2bfloat16(acc[mi][ni] + bea[n]);
        }
    }
}

// ---------- per-step 1: D2[64][2560] = h_bf(64,1024) @ W2^T + bias2 (MFMA) ----------
__global__ __launch_bounds__(256) void k_gemm2(const __hip_bfloat16* h_bf, const __hip_bfloat16* W2,
                                               const float* bias2, float* D2){
    int n0 = blockIdx.x * 64;
    int w = threadIdx.x >> 6;
    int l = threadIdx.x & 63;
    int lm = l & 15, lk = l >> 4;
    const short* hp = (const short*)h_bf + (size_t)(16*w + lm)*HID + 8*lk;
    const short* b0p = (const short*)W2 + (size_t)(n0      + lm)*HID + 8*lk;
    const short* b1p = (const short*)W2 + (size_t)(n0 + 16 + lm)*HID + 8*lk;
    const short* b2p = (const short*)W2 + (size_t)(n0 + 32 + lm)*HID + 8*lk;
    const short* b3p = (const short*)W2 + (size_t)(n0 + 48 + lm)*HID + 8*lk;
    f32x4 acc0 = {0.f,0.f,0.f,0.f}, acc1 = acc0, acc2 = acc0, acc3 = acc0;
    for (int kt = 0; kt < HID/32; ++kt){
        bf16x8 a = *(const bf16x8*)(hp + kt*32);
        bf16x8 b0 = *(const bf16x8*)(b0p + kt*32);
        bf16x8 b1 = *(const bf16x8*)(b1p + kt*32);
        bf16x8 b2 = *(const bf16x8*)(b2p + kt*32);
        bf16x8 b3 = *(const bf16x8*)(b3p + kt*32);
        acc0 = __builtin_amdgcn_mfma_f32_16x16x32_bf16(a, b0, acc0, 0,0,0);
        acc1 = __builtin_amdgcn_mfma_f32_16x16x32_bf16(a, b1, acc1, 0,0,0);
        acc2 = __builtin_amdgcn_mfma_f32_16x16x32_bf16(a, b2, acc2, 0,0,0);
        acc3 = __builtin_amdgcn_mfma_f32_16x16x32_bf16(a, b3, acc3, 0,0,0);
    }
    f32x4 av[4] = {acc0, acc1, acc2, acc3};
    #pragma unroll
    for (int nf = 0; nf < 4; ++nf){
        int n = n0 + 16*nf + lm;
        float bv = bias2[n];
        #pragma unroll
        for (int r = 0; r < 4; ++r){
            int m = 16*w + 4*lk + r;
            D2[m*N2 + n] = av[nf][r] + bv;
        }
    }
}

// ---------- per-step 2: e/softmax + context + gate -> gc (per-j block) ----------
__global__ __launch_bounds__(256) void k_att_ctx(const float* D2, const __hip_bfloat16* att1w,
        const float* wfa, const float* bfa, const __hip_bfloat16* img_s,
        const int* idx, const int* rank, const int* lens,
        float* outA, __hip_bfloat16* gcW, int t){
    int j = blockIdx.x, tid = threadIdx.x;
    __shared__ float att2L[ATT];
    __shared__ float wfaL[ATT];
    __shared__ float red[256];
    __shared__ float aL[P];
    int o = idx[j];
    int w = rank[j];
    int lj = lens[o];

    att2L[tid]     = D2[j*N2 + tid];
    att2L[tid+256] = D2[j*N2 + tid + 256];
    wfaL[tid] = wfa[tid];
    wfaL[tid+256] = wfa[tid+256];
    __syncthreads();

    float e = -1e30f;
    if (tid < P){
        const unsigned* ar = (const unsigned*)(att1w + ((size_t)(j*P + tid))*ATT);
        float acc = 0.f;
        #pragma unroll 4
        for (int q = 0; q < ATT/2; ++q){
            unsigned v = ar[q];
            float r0 = fmaxf(bf_lo(v) + att2L[2*q+0], 0.f);
            float r1 = fmaxf(bf_hi(v) + att2L[2*q+1], 0.f);
            acc += r0*wfaL[2*q+0] + r1*wfaL[2*q+1];
        }
        e = acc + bfa[0];
    }
    red[tid] = (tid < P) ? e : -1e30f;
    __syncthreads();
    for (int s = 128; s > 0; s >>= 1){
        if (tid < s) red[tid] = fmaxf(red[tid], red[tid+s]);
        __syncthreads();
    }
    float m = red[0];
    __syncthreads();
    float ex = (tid < P) ? __expf(e - m) : 0.f;
    red[tid] = ex;
    __syncthreads();
    for (int s = 128; s > 0; s >>= 1){
        if (tid < s) red[tid] += red[tid+s];
        __syncthreads();
    }
    float ssum = red[0];
    if (tid < P){
        float alpha = ex / ssum;
        aL[tid] = alpha;
        outA[((size_t)(w*T + t))*P + tid] = (t < lj) ? alpha : 0.f;
    }
    __syncthreads();

    // context + gate for 2048 dims, 2 per thread per strip
    const ushort* ib_base = (const ushort*)img_s + (size_t)j*P*ENC;
    #pragma unroll
    for (int s = 0; s < 4; ++s){
        int e0 = s*512 + tid*2;
        const ushort* ib = ib_base + e0;
        float c0 = 0.f, c1 = 0.f;
        #pragma unroll 4
        for (int p = 0; p < P; ++p){
            unsigned v = *(const unsigned*)(ib + (size_t)p*ENC);
            float a = aL[p];
            c0 += a * bf_lo(v);
            c1 += a * bf_hi(v);
        }
        float g0 = sigm(D2[j*N2 + ATT + e0]);
        float g1 = sigm(D2[j*N2 + ATT + e0 + 1]);
        gcW[j*ENC + e0]     = __float2bfloat16(g0*c0);
        gcW[j*ENC + e0 + 1] = __float2bfloat16(g1*c1);
    }
}

// ---------- per-step 3: gates MFMA GEMM + LSTM + outputs ----------
__global__ __launch_bounds__(256) void k_gates(const __hip_bfloat16* h_bf_in, const float* hIn,
        float* hOut, __hip_bfloat16* h_bf_out, float* cW,
        const __hip_bfloat16* gc, const __hip_bfloat16* emb_bf, const int* sent,
        const __hip_bfloat16* Wcat, const float* bsum,
        const int* idx, const int* rank, const int* lens,
        float* outH, int t){
    __shared__ float Dt[64][68];
    __shared__ int tokL[64], lensL[64], wLs[64];
    int tid = threadIdx.x;
    int nb = blockIdx.x;            // u-strip [16nb, 16nb+16)
    if (tid < 64){
        int o = idx[tid];
        tokL[tid] = sent[o*T + t];
        lensL[tid] = lens[o];
        wLs[tid] = rank[tid];
    }
    __syncthreads();

    int w = tid >> 6, l = tid & 63, lm = l & 15, lk = l >> 4;
    int mrow = 16*w + lm;
    int tok = tokL[mrow];
    const short* embp = (const short*)emb_bf + (size_t)tok*EMB + 8*lk;
    const short* gcp  = (const short*)gc   + (size_t)mrow*ENC + 8*lk - EMB;
    const short* hp   = (const short*)h_bf_in + (size_t)mrow*HID + 8*lk - (EMB+ENC);
    int n0 = nb*64;
    const short* br0 = (const short*)Wcat + (size_t)(n0      + lm)*KTOT + 8*lk;
    const short* br1 = (const short*)Wcat + (size_t)(n0 + 16 + lm)*KTOT + 8*lk;
    const short* br2 = (const short*)Wcat + (size_t)(n0 + 32 + lm)*KTOT + 8*lk;
    const short* br3 = (const short*)Wcat + (size_t)(n0 + 48 + lm)*KTOT + 8*lk;
    f32x4 acc0 = {0.f,0.f,0.f,0.f}, acc1 = acc0, acc2 = acc0, acc3 = acc0;

#define GSTEP(APTR, KOFF) { \
        bf16x8 a = *(const bf16x8*)((APTR) + (KOFF)); \
        bf16x8 b0 = *(const bf16x8*)(br0 + (KOFF)); \
        bf16x8 b1 = *(const bf16x8*)(br1 + (KOFF)); \
        bf16x8 b2 = *(const bf16x8*)(br2 + (KOFF)); \
        bf16x8 b3 = *(const bf16x8*)(br3 + (KOFF)); \
        acc0 = __builtin_amdgcn_mfma_f32_16x16x32_bf16(a, b0, acc0, 0,0,0); \
        acc1 = __builtin_amdgcn_mfma_f32_16x16x32_bf16(a, b1, acc1, 0,0,0); \
        acc2 = __builtin_amdgcn_mfma_f32_16x16x32_bf16(a, b2, acc2, 0,0,0); \
        acc3 = __builtin_amdgcn_mfma_f32_16x16x32_bf16(a, b3, acc3, 0,0,0); }

    for (int kt = 0; kt < EMB/32; ++kt)                 GSTEP(embp, kt*32);
    for (int kt = EMB/32; kt < (EMB+ENC)/32; ++kt)      GSTEP(gcp,  kt*32);
    for (int kt = (EMB+ENC)/32; kt < KTOT/32; ++kt)     GSTEP(hp,   kt*32);
#undef GSTEP

    f32x4 av[4] = {acc0, acc1, acc2, acc3};
    #pragma unroll
    for (int nf = 0; nf < 4; ++nf){
        float bv = bsum[n0 + 16*nf + lm];
        #pragma unroll
        for (int r = 0; r < 4; ++r){
            Dt[16*w + 4*lk + r][16*nf + lm] = av[nf][r] + bv;
        }
    }
    __syncthreads();

    int j = tid & 63;
    #pragma unroll
    for (int q = 0; q < 4; ++q){
        int ul = (tid >> 6) + q*4;
        int u = nb*16 + ul;
        float iv = Dt[j][4*ul+0];
        float fv = Dt[j][4*ul+1];
        float gv = Dt[j][4*ul+2];
        float ov = Dt[j][4*ul+3];
        float ig = sigm(iv), fg = sigm(fv), gg = tanhf(gv), og = sigm(ov);
        float cOld = cW[j*HID + u];
        float cNew = fg*cOld + ig*gg;
        float hNew = og*tanhf(cNew);
        bool active = (t < lensL[j]);
        float hOld = hIn[j*HID + u];
        float hKeep = active ? hNew : hOld;
        hOut[j*HID + u] = hKeep;
        h_bf_out[j*HID + u] = __float2bfloat16(hKeep);
        cW[j*HID + u] = active ? cNew : cOld;
        outH[((size_t)(wLs[j]*T + t))*HID + u] = active ? hNew : 0.f;
    }
}

extern "C" void kernel_launch(void* const* d_in, const int* in_sizes, int n_in,
                              void* d_out, int out_size, void* d_ws, size_t ws_size,
                              hipStream_t stream) {
    const float* img   = (const float*)d_in[0];
    const int*   sent  = (const int*)  d_in[1];
    const float* enc_h = (const float*)d_in[2];
    const float* enc_c = (const float*)d_in[3];
    const int*   lens  = (const int*)  d_in[4];
    const float* emb   = (const float*)d_in[5];
    const float* Wea   = (const float*)d_in[6];
    const float* bea   = (const float*)d_in[7];
    const float* Wda   = (const float*)d_in[8];
    const float* bda   = (const float*)d_in[9];
    const float* wfa   = (const float*)d_in[10];
    const float* bfa   = (const float*)d_in[11];
    const float* Wfb   = (const float*)d_in[12];
    const float* bfb   = (const float*)d_in[13];
    const float* Wih   = (const float*)d_in[14];
    const float* bih   = (const float*)d_in[15];
    const float* Whh   = (const float*)d_in[16];
    const float* bhh   = (const float*)d_in[17];

    float* outH = (float*)d_out;                       // [B,T,HID] f32
    float* outA = outH + (size_t)B*T*HID;              // [B,T,P]  f32

    char* wsb = (char*)d_ws;
    size_t off = 0;
    int* idxW  = (int*)(wsb + off); off += 256;
    int* rankW = (int*)(wsb + off); off += 256;
    __hip_bfloat16* att1w = (__hip_bfloat16*)(wsb + off); off += (size_t)B*P*ATT*2;       // 12.85MB
    __hip_bfloat16* img_s = (__hip_bfloat16*)(wsb + off); off += (size_t)B*P*ENC*2;       // 51.38MB
    __hip_bfloat16* emb_bf= (__hip_bfloat16*)(wsb + off); off += (size_t)10000*EMB*2;     // 10.24MB
    __hip_bfloat16* Wcat  = (__hip_bfloat16*)(wsb + off); off += (size_t)4*HID*KTOT*2;    // 29.36MB
    __hip_bfloat16* W2    = (__hip_bfloat16*)(wsb + off); off += (size_t)N2*HID*2;        // 5.24MB
    float* bsum  = (float*)(wsb + off); off += 4*HID*4;
    float* bias2 = (float*)(wsb + off); off += N2*4;
    float* hA    = (float*)(wsb + off); off += B*HID*4;
    float* hB    = (float*)(wsb + off); off += B*HID*4;
    float* cWs   = (float*)(wsb + off); off += B*HID*4;
    __hip_bfloat16* hbfA = (__hip_bfloat16*)(wsb + off); off += B*HID*2;
    __hip_bfloat16* hbfB = (__hip_bfloat16*)(wsb + off); off += B*HID*2;
    float* D2    = (float*)(wsb + off); off += (size_t)B*N2*4;
    __hip_bfloat16* gcW  = (__hip_bfloat16*)(wsb + off); off += B*ENC*2;

    k_sort<<<1, 64, 0, stream>>>(lens, idxW, rankW);
    k_init_hc<<<B, 256, 0, stream>>>(enc_h, enc_c, idxW, hA, cWs, hbfA);
    k_cvt_gates_w<<<4*HID, 256, 0, stream>>>(Wih, Whh, bih, bhh, Wcat, bsum);
    k_cvt_w2<<<N2, 256, 0, stream>>>(Wda, bda, Wfb, bfb, W2, bias2);
    k_cvt_emb<<<20000, 256, 0, stream>>>(emb, emb_bf);
    k_cvt_img<<<dim3(P*ENC/256, B), 256, 0, stream>>>(img, idxW, img_s);
    k_att1<<<dim3((B*P)/64, ATT/128), 256, 0, stream>>>(img, Wea, bea, idxW, att1w);

    for (int t = 0; t < T; ++t){
        const float* hIn = (t & 1) ? hB : hA;
        float*       hOut = (t & 1) ? hA : hB;
        const __hip_bfloat16* hbfIn  = (t & 1) ? hbfB : hbfA;
        __hip_bfloat16*       hbfOut = (t & 1) ? hbfA : hbfB;
        k_gemm2<<<N2/64, 256, 0, stream>>>(hbfIn, W2, bias2, D2);
        k_att_ctx<<<B, 256, 0, stream>>>(D2, att1w, wfa, bfa, img_s,
                                         idxW, rankW, lens, outA, gcW, t);
        k_gates<<<HID/16, 256, 0, stream>>>(hbfIn, hIn, hOut, hbfOut, cWs,
                                            gcW, emb_bf, sent, Wcat, bsum,
                                            idxW, rankW, lens, outH, t);
    }
}

// Round 5
// 26717.697 us; speedup vs baseline: 1.7811x; 1.0743x over previous
//
#include <hip/hip_runtime.h>
#include <hip/hip_bf16.h>
#include <hip/hip_cooperative_groups.h>
#include <math.h>

namespace cg = cooperative_groups;

#define B 64
#define T 160
#define P 196
#define ENC 2048
#define ATT 512
#define EMB 512
#define HID 1024
#define KTOT 3584   // EMB + ENC + HID
#define N2 2560     // ATT + ENC

typedef __attribute__((ext_vector_type(8))) short bf16x8;
typedef __attribute__((ext_vector_type(4))) float f32x4;

__device__ __forceinline__ float sigm(float x){ return 1.0f/(1.0f+__expf(-x)); }
__device__ __forceinline__ float bfu(short s){ return __uint_as_float(((unsigned)(unsigned short)s) << 16); }

// ---------- sort: stable descending by lens ----------
__global__ void k_sort(const int* lens, int* idx, int* rank){
    __shared__ int L[B];
    int i = threadIdx.x;
    L[i] = lens[i];
    __syncthreads();
    int li = L[i];
    int r = 0;
    for (int j = 0; j < B; ++j){
        int lj = L[j];
        if (lj > li || (lj == li && j < i)) r++;
    }
    rank[i] = r;
    idx[r] = i;
}

// ---------- init h0/c0 (sorted order) + bf16 copy ----------
__global__ void k_init_hc(const float* enc_h, const float* enc_c, const int* idx,
                          float* h, float* c, __hip_bfloat16* h_bf){
    int j = blockIdx.x;
    int o = idx[j];
    for (int k = threadIdx.x; k < HID; k += blockDim.x){
        float hv = (k < 512) ? enc_h[o*512 + k] : enc_h[B*512 + o*512 + (k-512)];
        float cv = (k < 512) ? enc_c[o*512 + k] : enc_c[B*512 + o*512 + (k-512)];
        h[j*HID + k] = hv;
        c[j*HID + k] = cv;
        h_bf[j*HID + k] = __float2bfloat16(hv);
    }
}

// ---------- weight conversions (once) ----------
__global__ void k_cvt_gates_w(const float* Wih, const float* Whh, const float* bih, const float* bhh,
                              __hip_bfloat16* Wcat, float* bsum){
    int n = blockIdx.x;              // 0..4095, n = 4u+g
    int u = n >> 2, g = n & 3;
    int r = g*HID + u;
    const float* s1 = Wih + (size_t)r*(EMB+ENC);
    const float* s2 = Whh + (size_t)r*HID;
    __hip_bfloat16* dst = Wcat + (size_t)n*KTOT;
    for (int k = threadIdx.x; k < EMB+ENC; k += 256) dst[k] = __float2bfloat16(s1[k]);
    for (int k = threadIdx.x; k < HID; k += 256) dst[EMB+ENC+k] = __float2bfloat16(s2[k]);
    if (threadIdx.x == 0) bsum[n] = bih[r] + bhh[r];
}

__global__ void k_cvt_w2(const float* Wda, const float* bda, const float* Wfb, const float* bfb,
                         __hip_bfloat16* W2, float* bias2){
    int n = blockIdx.x;              // 0..2559
    const float* src = (n < ATT) ? (Wda + (size_t)n*HID) : (Wfb + (size_t)(n-ATT)*HID);
    __hip_bfloat16* dst = W2 + (size_t)n*HID;
    for (int k = threadIdx.x; k < HID; k += 256) dst[k] = __float2bfloat16(src[k]);
    if (threadIdx.x == 0) bias2[n] = (n < ATT) ? bda[n] : bfb[n-ATT];
}

__global__ void k_cvt_emb(const float* emb, __hip_bfloat16* emb_bf){
    size_t i = (size_t)blockIdx.x*256 + threadIdx.x;
    emb_bf[i] = __float2bfloat16(emb[i]);
}

__global__ void k_cvt_wea(const float* Wea, __hip_bfloat16* Wea_bf){
    int n = blockIdx.x;              // 0..511
    for (int k = threadIdx.x; k < ENC; k += 256)
        Wea_bf[(size_t)n*ENC + k] = __float2bfloat16(Wea[(size_t)n*ENC + k]);
}

__global__ void k_cvt_img(const float* img, const int* idx, __hip_bfloat16* img_s){
    int j = blockIdx.y;
    int o = idx[j];
    size_t off = (size_t)blockIdx.x*256 + threadIdx.x;
    img_s[(size_t)j*P*ENC + off] = __float2bfloat16(img[(size_t)o*P*ENC + off]);
}

// ---------- att1 (once, MFMA): att1w[m][n] = img_s[m,:]·Wea[n,:] + bea[n], m=j*P+p ----------
__global__ __launch_bounds__(256) void k_att1m(const __hip_bfloat16* img_s, const __hip_bfloat16* Wea_bf,
                                               const float* bea, __hip_bfloat16* att1w){
    int m0 = blockIdx.x * 64, n0 = blockIdx.y * 64;
    int tid = threadIdx.x, w = tid >> 6, l = tid & 63, lm = l & 15, lk = l >> 4;
    const short* ap = (const short*)img_s + (size_t)(m0 + 16*w + lm)*ENC + 8*lk;
    const short* bp = (const short*)Wea_bf + (size_t)(n0 + lm)*ENC + 8*lk;
    f32x4 acc[4];
    #pragma unroll
    for (int nt=0; nt<4; ++nt) acc[nt] = (f32x4){0.f,0.f,0.f,0.f};
    #pragma unroll 4
    for (int kt = 0; kt < ENC/32; ++kt){
        bf16x8 a = *(const bf16x8*)(ap + kt*32);
        #pragma unroll
        for (int nt=0; nt<4; ++nt){
            bf16x8 bb = *(const bf16x8*)(bp + (size_t)nt*16*ENC + kt*32);
            acc[nt] = __builtin_amdgcn_mfma_f32_16x16x32_bf16(a, bb, acc[nt], 0,0,0);
        }
    }
    #pragma unroll
    for (int nt=0; nt<4; ++nt){
        int n = n0 + nt*16 + lm;
        float bv = bea[n];
        #pragma unroll
        for (int r=0; r<4; ++r){
            int m = m0 + 16*w + 4*lk + r;
            att1w[(size_t)m*ATT + n] = __float2bfloat16(acc[nt][r] + bv);
        }
    }
}

// ---------- persistent cooperative scan kernel ----------
struct SP {
    const __hip_bfloat16 *att1w, *img_s, *emb_bf, *Wcat, *W2;
    const float *bsum, *bias2, *wfa, *bfa;
    const int *sent, *idx, *rank, *lens;
    float *D2;
    __hip_bfloat16 *gc;
    float *hF0, *hF1, *cW;
    __hip_bfloat16 *hb0, *hb1;
    float *outH, *outA;
};

__global__ __launch_bounds__(256) void k_scan(SP p){
    cg::grid_group grid = cg::this_grid();
    __shared__ union {
        struct {
            float att2L[512];
            float wfaL[512];
            float red[256];
            float aL[200];
            float ctxP[4][512];
        } p23;
        struct {
            float Dt[64][17];
            int tokL[64], lensL[64], wLs[64];
        } p4;
    } sh;

    int b = blockIdx.x;
    int tid = threadIdx.x;
    int w = tid >> 6, l = tid & 63, lm = l & 15, lk = l >> 4;
    float bfa0 = p.bfa[0];

    for (int t = 0; t < T; ++t){
        const __hip_bfloat16* hbIn = (t & 1) ? p.hb1 : p.hb0;
        __hip_bfloat16*       hbOut = (t & 1) ? p.hb0 : p.hb1;
        const float* hFIn = (t & 1) ? p.hF1 : p.hF0;
        float*       hFOut = (t & 1) ? p.hF0 : p.hF1;

        // ---- phase 1: D2[64][2560] = h_bf @ W2^T + bias2 ----
        if (b < N2/16){
            int n0 = b*16;
            const short* ap = (const short*)hbIn + (size_t)(16*w + lm)*HID + 8*lk;
            const short* bp = (const short*)p.W2 + (size_t)(n0 + lm)*HID + 8*lk;
            f32x4 acc = {0.f,0.f,0.f,0.f};
            #pragma unroll 8
            for (int kt = 0; kt < HID/32; ++kt){
                bf16x8 a = *(const bf16x8*)(ap + kt*32);
                bf16x8 bb = *(const bf16x8*)(bp + kt*32);
                acc = __builtin_amdgcn_mfma_f32_16x16x32_bf16(a, bb, acc, 0,0,0);
            }
            float bv = p.bias2[n0 + lm];
            #pragma unroll
            for (int r=0; r<4; ++r)
                p.D2[(16*w + 4*lk + r)*N2 + n0 + lm] = acc[r] + bv;
        }
        grid.sync();

        // ---- phase 2+3: e + softmax + context + gc ; block = (j, quarter q) ----
        {
            int j = b >> 2, q = b & 3;
            int o = p.idx[j];
            int wj = p.rank[j];
            int lj = p.lens[o];

            sh.p23.att2L[tid]     = p.D2[j*N2 + tid];
            sh.p23.att2L[tid+256] = p.D2[j*N2 + tid + 256];
            sh.p23.wfaL[tid]      = p.wfa[tid];
            sh.p23.wfaL[tid+256]  = p.wfa[tid+256];
            __syncthreads();

            float e = -1e30f;
            if (tid < P){
                const short* ar = (const short*)p.att1w + (size_t)(j*P + tid)*ATT;
                float acc = 0.f;
                #pragma unroll 8
                for (int k8 = 0; k8 < ATT/8; ++k8){
                    bf16x8 v = *(const bf16x8*)(ar + k8*8);
                    #pragma unroll
                    for (int z=0; z<8; ++z)
                        acc += fmaxf(bfu(v[z]) + sh.p23.att2L[k8*8+z], 0.f) * sh.p23.wfaL[k8*8+z];
                }
                e = acc + bfa0;
            }
            sh.p23.red[tid] = (tid < P) ? e : -1e30f;
            __syncthreads();
            for (int s = 128; s > 0; s >>= 1){
                if (tid < s) sh.p23.red[tid] = fmaxf(sh.p23.red[tid], sh.p23.red[tid+s]);
                __syncthreads();
            }
            float m = sh.p23.red[0];
            __syncthreads();
            float ex = (tid < P) ? __expf(e - m) : 0.f;
            sh.p23.red[tid] = ex;
            __syncthreads();
            for (int s = 128; s > 0; s >>= 1){
                if (tid < s) sh.p23.red[tid] += sh.p23.red[tid+s];
                __syncthreads();
            }
            float ssum = sh.p23.red[0];
            __syncthreads();
            if (tid < P){
                float alpha = ex / ssum;
                sh.p23.aL[tid] = alpha;
                if (q == 0)
                    p.outA[((size_t)(wj*T + t))*P + tid] = (t < lj) ? alpha : 0.f;
            }
            __syncthreads();

            // context quarter: dims [q*512, q*512+512); wave w takes p = w, w+4, ...
            const short* ib = (const short*)p.img_s + (size_t)j*P*ENC + q*512 + l*8;
            float a8[8];
            #pragma unroll
            for (int z=0; z<8; ++z) a8[z] = 0.f;
            #pragma unroll 4
            for (int i = 0; i < P/4; ++i){
                int pp = w + 4*i;
                bf16x8 v = *(const bf16x8*)(ib + (size_t)pp*ENC);
                float al = sh.p23.aL[pp];
                #pragma unroll
                for (int z=0; z<8; ++z) a8[z] += al * bfu(v[z]);
            }
            #pragma unroll
            for (int z=0; z<8; ++z) sh.p23.ctxP[w][l*8+z] = a8[z];
            __syncthreads();
            #pragma unroll
            for (int rep=0; rep<2; ++rep){
                int d = tid + rep*256;
                float ctx = sh.p23.ctxP[0][d] + sh.p23.ctxP[1][d] + sh.p23.ctxP[2][d] + sh.p23.ctxP[3][d];
                int eg = q*512 + d;
                float gate = sigm(p.D2[j*N2 + ATT + eg]);
                p.gc[j*ENC + eg] = __float2bfloat16(gate*ctx);
            }
        }
        grid.sync();

        // ---- phase 4: gates GEMM (64 x 16cols x K=3584) + LSTM + outputs ----
        {
            if (tid < 64){
                int o = p.idx[tid];
                sh.p4.tokL[tid] = p.sent[o*T + t];
                sh.p4.lensL[tid] = p.lens[o];
                sh.p4.wLs[tid] = p.rank[tid];
            }
            __syncthreads();

            int n0 = b*16;
            int mrow = 16*w + lm;
            int tok = sh.p4.tokL[mrow];
            const short* aEmb = (const short*)p.emb_bf + (size_t)tok*EMB + 8*lk;
            const short* aGc  = (const short*)p.gc + (size_t)mrow*ENC + 8*lk;
            const short* aH   = (const short*)hbIn + (size_t)mrow*HID + 8*lk;
            const short* bp   = (const short*)p.Wcat + (size_t)(n0 + lm)*KTOT + 8*lk;
            f32x4 acc = {0.f,0.f,0.f,0.f};
            #pragma unroll 4
            for (int kt = 0; kt < EMB/32; ++kt){
                bf16x8 a = *(const bf16x8*)(aEmb + kt*32);
                bf16x8 bb = *(const bf16x8*)(bp + kt*32);
                acc = __builtin_amdgcn_mfma_f32_16x16x32_bf16(a, bb, acc, 0,0,0);
            }
            #pragma unroll 8
            for (int kt = 0; kt < ENC/32; ++kt){
                bf16x8 a = *(const bf16x8*)(aGc + kt*32);
                bf16x8 bb = *(const bf16x8*)(bp + (EMB/32 + kt)*32);
                acc = __builtin_amdgcn_mfma_f32_16x16x32_bf16(a, bb, acc, 0,0,0);
            }
            #pragma unroll 8
            for (int kt = 0; kt < HID/32; ++kt){
                bf16x8 a = *(const bf16x8*)(aH + kt*32);
                bf16x8 bb = *(const bf16x8*)(bp + ((EMB+ENC)/32 + kt)*32);
                acc = __builtin_amdgcn_mfma_f32_16x16x32_bf16(a, bb, acc, 0,0,0);
            }
            float bv = p.bsum[n0 + lm];
            #pragma unroll
            for (int r=0; r<4; ++r)
                sh.p4.Dt[16*w + 4*lk + r][lm] = acc[r] + bv;
            __syncthreads();

            int j = tid & 63, ul = tid >> 6;
            int u = b*4 + ul;
            float iv = sh.p4.Dt[j][4*ul+0];
            float fv = sh.p4.Dt[j][4*ul+1];
            float gv = sh.p4.Dt[j][4*ul+2];
            float ov = sh.p4.Dt[j][4*ul+3];
            float ig = sigm(iv), fg = sigm(fv), gg = tanhf(gv), og = sigm(ov);
            float cOld = p.cW[j*HID + u];
            float cNew = fg*cOld + ig*gg;
            float hNew = og*tanhf(cNew);
            bool active = (t < sh.p4.lensL[j]);
            float hOld = hFIn[j*HID + u];
            float hKeep = active ? hNew : hOld;
            hFOut[j*HID + u] = hKeep;
            hbOut[j*HID + u] = __float2bfloat16(hKeep);
            p.cW[j*HID + u] = active ? cNew : cOld;
            p.outH[((size_t)sh.p4.wLs[j]*T + t)*HID + u] = active ? hNew : 0.f;
        }
        grid.sync();
    }
}

extern "C" void kernel_launch(void* const* d_in, const int* in_sizes, int n_in,
                              void* d_out, int out_size, void* d_ws, size_t ws_size,
                              hipStream_t stream) {
    const float* img   = (const float*)d_in[0];
    const int*   sent  = (const int*)  d_in[1];
    const float* enc_h = (const float*)d_in[2];
    const float* enc_c = (const float*)d_in[3];
    const int*   lens  = (const int*)  d_in[4];
    const float* emb   = (const float*)d_in[5];
    const float* Wea   = (const float*)d_in[6];
    const float* bea   = (const float*)d_in[7];
    const float* Wda   = (const float*)d_in[8];
    const float* bda   = (const float*)d_in[9];
    const float* wfa   = (const float*)d_in[10];
    const float* bfa   = (const float*)d_in[11];
    const float* Wfb   = (const float*)d_in[12];
    const float* bfb   = (const float*)d_in[13];
    const float* Wih   = (const float*)d_in[14];
    const float* bih   = (const float*)d_in[15];
    const float* Whh   = (const float*)d_in[16];
    const float* bhh   = (const float*)d_in[17];

    float* outH = (float*)d_out;                       // [B,T,HID] f32
    float* outA = outH + (size_t)B*T*HID;              // [B,T,P]  f32

    char* wsb = (char*)d_ws;
    size_t off = 0;
    int* idxW  = (int*)(wsb + off); off += 256;
    int* rankW = (int*)(wsb + off); off += 256;
    __hip_bfloat16* att1w = (__hip_bfloat16*)(wsb + off); off += (size_t)B*P*ATT*2;       // 12.85MB
    __hip_bfloat16* img_s = (__hip_bfloat16*)(wsb + off); off += (size_t)B*P*ENC*2;       // 51.38MB
    __hip_bfloat16* emb_bf= (__hip_bfloat16*)(wsb + off); off += (size_t)10000*EMB*2;     // 10.24MB
    __hip_bfloat16* Wcat  = (__hip_bfloat16*)(wsb + off); off += (size_t)4*HID*KTOT*2;    // 29.36MB
    __hip_bfloat16* W2    = (__hip_bfloat16*)(wsb + off); off += (size_t)N2*HID*2;        // 5.24MB
    __hip_bfloat16* Wea_bf= (__hip_bfloat16*)(wsb + off); off += (size_t)ATT*ENC*2;       // 2.10MB
    float* bsum  = (float*)(wsb + off); off += 4*HID*4;
    float* bias2 = (float*)(wsb + off); off += N2*4;
    float* hA    = (float*)(wsb + off); off += B*HID*4;
    float* hB    = (float*)(wsb + off); off += B*HID*4;
    float* cWs   = (float*)(wsb + off); off += B*HID*4;
    __hip_bfloat16* hbfA = (__hip_bfloat16*)(wsb + off); off += B*HID*2;
    __hip_bfloat16* hbfB = (__hip_bfloat16*)(wsb + off); off += B*HID*2;
    float* D2    = (float*)(wsb + off); off += (size_t)B*N2*4;
    __hip_bfloat16* gcW  = (__hip_bfloat16*)(wsb + off); off += B*ENC*2;

    k_sort<<<1, 64, 0, stream>>>(lens, idxW, rankW);
    k_init_hc<<<B, 256, 0, stream>>>(enc_h, enc_c, idxW, hA, cWs, hbfA);
    k_cvt_gates_w<<<4*HID, 256, 0, stream>>>(Wih, Whh, bih, bhh, Wcat, bsum);
    k_cvt_w2<<<N2, 256, 0, stream>>>(Wda, bda, Wfb, bfb, W2, bias2);
    k_cvt_emb<<<20000, 256, 0, stream>>>(emb, emb_bf);
    k_cvt_wea<<<ATT, 256, 0, stream>>>(Wea, Wea_bf);
    k_cvt_img<<<dim3(P*ENC/256, B), 256, 0, stream>>>(img, idxW, img_s);
    k_att1m<<<dim3((B*P)/64, ATT/64), 256, 0, stream>>>(img_s, Wea_bf, bea, att1w);

    SP sp;
    sp.att1w = att1w; sp.img_s = img_s; sp.emb_bf = emb_bf; sp.Wcat = Wcat; sp.W2 = W2;
    sp.bsum = bsum; sp.bias2 = bias2; sp.wfa = wfa; sp.bfa = bfa;
    sp.sent = sent; sp.idx = idxW; sp.rank = rankW; sp.lens = lens;
    sp.D2 = D2; sp.gc = gcW;
    sp.hF0 = hA; sp.hF1 = hB; sp.cW = cWs;
    sp.hb0 = hbfA; sp.hb1 = hbfB;
    sp.outH = outH; sp.outA = outA;

    void* args[] = { &sp };
    hipLaunchCooperativeKernel(reinterpret_cast<void*>(k_scan), dim3(256), dim3(256),
                               args, 0, stream);
}

// Round 6
// 25538.046 us; speedup vs baseline: 1.8633x; 1.0462x over previous
//
#include <hip/hip_runtime.h>
#include <hip/hip_bf16.h>
#include <hip/hip_cooperative_groups.h>
#include <math.h>

namespace cg = cooperative_groups;

#define B 64
#define T 160
#define P 196
#define ENC 2048
#define ATT 512
#define EMB 512
#define HID 1024
#define KTOT 3584   // EMB + ENC + HID
#define N2 2560     // ATT + ENC
#define KT4 112     // KTOT/32
#define NTHR 512

typedef __attribute__((ext_vector_type(8))) short bf16x8;
typedef __attribute__((ext_vector_type(4))) float f32x4;

__device__ __forceinline__ float sigm(float x){ return 1.0f/(1.0f+__expf(-x)); }
__device__ __forceinline__ float bfu(short s){ return __uint_as_float(((unsigned)(unsigned short)s) << 16); }

// ---------- sort: stable descending by lens ----------
__global__ void k_sort(const int* lens, int* idx, int* rank){
    __shared__ int L[B];
    int i = threadIdx.x;
    L[i] = lens[i];
    __syncthreads();
    int li = L[i];
    int r = 0;
    for (int j = 0; j < B; ++j){
        int lj = L[j];
        if (lj > li || (lj == li && j < i)) r++;
    }
    rank[i] = r;
    idx[r] = i;
}

// ---------- init h0/c0 (sorted order) + bf16 copy ----------
__global__ void k_init_hc(const float* enc_h, const float* enc_c, const int* idx,
                          float* h, float* c, __hip_bfloat16* h_bf){
    int j = blockIdx.x;
    int o = idx[j];
    for (int k = threadIdx.x; k < HID; k += blockDim.x){
        float hv = (k < 512) ? enc_h[o*512 + k] : enc_h[B*512 + o*512 + (k-512)];
        float cv = (k < 512) ? enc_c[o*512 + k] : enc_c[B*512 + o*512 + (k-512)];
        h[j*HID + k] = hv;
        c[j*HID + k] = cv;
        h_bf[j*HID + k] = __float2bfloat16(hv);
    }
}

// ---------- Wcat in per-strip MFMA-fragment order (once) ----------
// Wfrag[((strip*112 + kt)*64 + lane)*8 + e] = W[r][k],
//   n = strip*16 + (lane&15); r = (n&3)*HID + (n>>2); k = kt*32 + (lane>>4)*8 + e
__global__ void k_cvt_wcat(const float* Wih, const float* Whh, __hip_bfloat16* Wfrag){
    size_t i = (size_t)blockIdx.x*256 + threadIdx.x;   // 57,344 blocks -> 14,680,064
    int e = (int)(i & 7);
    size_t t2 = i >> 3;
    int lane = (int)(t2 & 63);
    size_t t3 = t2 >> 6;
    int kt = (int)(t3 % KT4);
    int strip = (int)(t3 / KT4);
    int n = strip*16 + (lane & 15);
    int r = (n & 3)*HID + (n >> 2);
    int k = kt*32 + (lane >> 4)*8 + e;
    float v = (k < EMB+ENC) ? Wih[(size_t)r*(EMB+ENC) + k]
                            : Whh[(size_t)r*HID + (k - EMB - ENC)];
    Wfrag[i] = __float2bfloat16(v);
}

__global__ void k_bsum(const float* bih, const float* bhh, float* bsum){
    int n = blockIdx.x*256 + threadIdx.x;   // 16 blocks -> 4096
    int r = (n & 3)*HID + (n >> 2);
    bsum[n] = bih[r] + bhh[r];
}

__global__ void k_cvt_w2(const float* Wda, const float* bda, const float* Wfb, const float* bfb,
                         __hip_bfloat16* W2, float* bias2){
    int n = blockIdx.x;              // 0..2559
    const float* src = (n < ATT) ? (Wda + (size_t)n*HID) : (Wfb + (size_t)(n-ATT)*HID);
    __hip_bfloat16* dst = W2 + (size_t)n*HID;
    for (int k = threadIdx.x; k < HID; k += 256) dst[k] = __float2bfloat16(src[k]);
    if (threadIdx.x == 0) bias2[n] = (n < ATT) ? bda[n] : bfb[n-ATT];
}

__global__ void k_cvt_emb(const float* emb, __hip_bfloat16* emb_bf){
    size_t i = (size_t)blockIdx.x*256 + threadIdx.x;
    emb_bf[i] = __float2bfloat16(emb[i]);
}

__global__ void k_cvt_wea(const float* Wea, __hip_bfloat16* Wea_bf){
    int n = blockIdx.x;
    for (int k = threadIdx.x; k < ENC; k += 256)
        Wea_bf[(size_t)n*ENC + k] = __float2bfloat16(Wea[(size_t)n*ENC + k]);
}

__global__ void k_cvt_img(const float* img, const int* idx, __hip_bfloat16* img_s){
    int j = blockIdx.y;
    int o = idx[j];
    size_t off = (size_t)blockIdx.x*256 + threadIdx.x;
    img_s[(size_t)j*P*ENC + off] = __float2bfloat16(img[(size_t)o*P*ENC + off]);
}

// ---------- att1 (once, MFMA) ----------
__global__ __launch_bounds__(256) void k_att1m(const __hip_bfloat16* img_s, const __hip_bfloat16* Wea_bf,
                                               const float* bea, __hip_bfloat16* att1w){
    int m0 = blockIdx.x * 64, n0 = blockIdx.y * 64;
    int tid = threadIdx.x, w = tid >> 6, l = tid & 63, lm = l & 15, lk = l >> 4;
    const short* ap = (const short*)img_s + (size_t)(m0 + 16*w + lm)*ENC + 8*lk;
    const short* bp = (const short*)Wea_bf + (size_t)(n0 + lm)*ENC + 8*lk;
    f32x4 acc[4];
    #pragma unroll
    for (int nt=0; nt<4; ++nt) acc[nt] = (f32x4){0.f,0.f,0.f,0.f};
    #pragma unroll 4
    for (int kt = 0; kt < ENC/32; ++kt){
        bf16x8 a = *(const bf16x8*)(ap + kt*32);
        #pragma unroll
        for (int nt=0; nt<4; ++nt){
            bf16x8 bb = *(const bf16x8*)(bp + (size_t)nt*16*ENC + kt*32);
            acc[nt] = __builtin_amdgcn_mfma_f32_16x16x32_bf16(a, bb, acc[nt], 0,0,0);
        }
    }
    #pragma unroll
    for (int nt=0; nt<4; ++nt){
        int n = n0 + nt*16 + lm;
        float bv = bea[n];
        #pragma unroll
        for (int r=0; r<4; ++r){
            int m = m0 + 16*w + 4*lk + r;
            att1w[(size_t)m*ATT + n] = __float2bfloat16(acc[nt][r] + bv);
        }
    }
}

// ---------- persistent cooperative scan ----------
struct SP {
    const __hip_bfloat16 *att1w, *img_s, *emb_bf, *Wfrag, *W2;
    const float *bsum, *bias2, *wfa, *bfa;
    const int *sent, *idx, *rank, *lens;
    float *D2, *eP;
    __hip_bfloat16 *gc;
    float *hF0, *hF1, *cW;
    __hip_bfloat16 *hb0, *hb1;
    float *outH, *outA;
};

__global__ __launch_bounds__(512) void k_scan(SP p){
    cg::grid_group grid = cg::this_grid();
    __shared__ short WcatL[KT4*64*8];          // 114,688 B, fragment-ordered
    __shared__ union {
        struct { float Dp[2][64][17]; int tokL[64], lensL[64], wLs[64]; } gem;
        struct { float att2q[128]; float wfaq[128]; float red[512]; } p2;
        struct { float red[512]; float aL[200]; float ctxP[4][512]; } p3;
    } sh;

    int b = blockIdx.x, tid = threadIdx.x;
    int w = tid >> 6, l = tid & 63, lm = l & 15, lk = l >> 4;

    // one-time LDS fill (straight copy, frag order)
    {
        const bf16x8* src = (const bf16x8*)((const short*)p.Wfrag + (size_t)b*KT4*64*8);
        bf16x8* dst = (bf16x8*)WcatL;
        #pragma unroll
        for (int i = 0; i < KT4*64/NTHR; ++i) dst[tid + i*NTHR] = src[tid + i*NTHR];
    }
    __syncthreads();

    float bfa0 = p.bfa[0];

    for (int t = 0; t < T; ++t){
        const __hip_bfloat16* hbIn = (t & 1) ? p.hb1 : p.hb0;
        __hip_bfloat16*       hbOut = (t & 1) ? p.hb0 : p.hb1;
        const float* hFIn = (t & 1) ? p.hF1 : p.hF0;
        float*       hFOut = (t & 1) ? p.hF0 : p.hF1;

        // ---- P1: D2[64][2560] = h_bf @ W2^T + bias2 ; blocks < 160, K-split waves ----
        if (b < N2/16){
            int n0 = b*16;
            int rt = w & 3, kh = w >> 2;
            const short* ap = (const short*)hbIn + (size_t)(16*rt + lm)*HID + kh*512 + 8*lk;
            const short* bp = (const short*)p.W2 + (size_t)(n0 + lm)*HID + kh*512 + 8*lk;
            f32x4 acc = {0.f,0.f,0.f,0.f};
            #pragma unroll 8
            for (int kt = 0; kt < 16; ++kt){
                bf16x8 a = *(const bf16x8*)(ap + kt*32);
                bf16x8 bb = *(const bf16x8*)(bp + kt*32);
                acc = __builtin_amdgcn_mfma_f32_16x16x32_bf16(a, bb, acc, 0,0,0);
            }
            #pragma unroll
            for (int r=0; r<4; ++r) sh.gem.Dp[kh][16*rt + 4*lk + r][lm] = acc[r];
            __syncthreads();
            #pragma unroll
            for (int e2=0; e2<2; ++e2){
                int ii = tid + e2*512;
                int m = ii >> 4, nl = ii & 15;
                p.D2[m*N2 + n0 + nl] = sh.gem.Dp[0][m][nl] + sh.gem.Dp[1][m][nl] + p.bias2[n0 + nl];
            }
        }
        grid.sync();

        // ---- P2: partial e over ATT quarter ; block = (j=b&63, aq=b>>6) ----
        {
            int j = b & 63, aq = b >> 6;
            if (tid < 128){
                sh.p2.att2q[tid] = p.D2[j*N2 + aq*128 + tid];
                sh.p2.wfaq[tid]  = p.wfa[aq*128 + tid];
            }
            __syncthreads();
            int pp = tid & 255, ah = tid >> 8;
            float acc = 0.f;
            if (pp < P){
                const short* ar = (const short*)p.att1w + (size_t)(j*P + pp)*ATT + aq*128 + ah*64;
                #pragma unroll 4
                for (int k8 = 0; k8 < 8; ++k8){
                    bf16x8 v = *(const bf16x8*)(ar + k8*8);
                    #pragma unroll
                    for (int z=0; z<8; ++z){
                        int a = ah*64 + k8*8 + z;
                        acc += fmaxf(bfu(v[z]) + sh.p2.att2q[a], 0.f) * sh.p2.wfaq[a];
                    }
                }
            }
            sh.p2.red[tid] = acc;
            __syncthreads();
            if (tid < P) p.eP[(j*4 + aq)*200 + tid] = sh.p2.red[tid] + sh.p2.red[tid + 256];
        }
        grid.sync();

        // ---- P3: finish e + softmax + context + gc ; block = (j=b&63, q=b>>6) ----
        {
            int j = b & 63, q = b >> 6;
            int o = p.idx[j], wj = p.rank[j], lj = p.lens[o];
            float e = -1e30f;
            if (tid < P){
                const float* ep = p.eP + j*800 + tid;
                e = ep[0] + ep[200] + ep[400] + ep[600] + bfa0;
            }
            sh.p3.red[tid] = e;
            __syncthreads();
            for (int s = 256; s > 0; s >>= 1){
                if (tid < s) sh.p3.red[tid] = fmaxf(sh.p3.red[tid], sh.p3.red[tid+s]);
                __syncthreads();
            }
            float m = sh.p3.red[0];
            __syncthreads();
            float ex = (tid < P) ? __expf(e - m) : 0.f;
            sh.p3.red[tid] = ex;
            __syncthreads();
            for (int s = 256; s > 0; s >>= 1){
                if (tid < s) sh.p3.red[tid] += sh.p3.red[tid+s];
                __syncthreads();
            }
            float ssum = sh.p3.red[0];
            if (tid < P){
                float alpha = ex / ssum;
                sh.p3.aL[tid] = alpha;
                if (q == 0) p.outA[((size_t)(wj*T + t))*P + tid] = (t < lj) ? alpha : 0.f;
            }
            if (tid >= P && tid < 200) sh.p3.aL[tid] = 0.f;
            __syncthreads();

            // context quarter [q*512, q*512+512): wave w takes p = w, w+8, ... (padded to 200)
            const short* ib = (const short*)p.img_s + (size_t)j*P*ENC + q*512 + l*8;
            float a8[8];
            #pragma unroll
            for (int z=0; z<8; ++z) a8[z] = 0.f;
            #pragma unroll 5
            for (int i = 0; i < 25; ++i){
                int pp = w + 8*i;
                bf16x8 v = *(const bf16x8*)(ib + (size_t)pp*ENC);
                float al = sh.p3.aL[pp];
                #pragma unroll
                for (int z=0; z<8; ++z) a8[z] += al * bfu(v[z]);
            }
            if (w < 4){
                #pragma unroll
                for (int z=0; z<8; ++z) sh.p3.ctxP[w][l*8+z] = a8[z];
            }
            __syncthreads();
            if (w >= 4){
                #pragma unroll
                for (int z=0; z<8; ++z) sh.p3.ctxP[w-4][l*8+z] += a8[z];
            }
            __syncthreads();
            {
                int d = tid;
                float ctx = sh.p3.ctxP[0][d] + sh.p3.ctxP[1][d] + sh.p3.ctxP[2][d] + sh.p3.ctxP[3][d];
                int eg = q*512 + d;
                float gate = sigm(p.D2[j*N2 + ATT + eg]);
                p.gc[j*ENC + eg] = __float2bfloat16(gate*ctx);
            }
        }
        grid.sync();

        // ---- P4: gates GEMM (K-split waves, B from LDS) + LSTM + outputs ----
        {
            if (tid < 64){
                int o = p.idx[tid];
                sh.gem.tokL[tid] = p.sent[o*T + t];
                sh.gem.lensL[tid] = p.lens[o];
                sh.gem.wLs[tid] = p.rank[tid];
            }
            __syncthreads();
            int rt = w & 3, kh = w >> 2;
            int mrow = 16*rt + lm;
            int tok = sh.gem.tokL[mrow];
            const short* aEmb = (const short*)p.emb_bf + (size_t)tok*EMB + 8*lk;
            const short* aGc  = (const short*)p.gc + (size_t)mrow*ENC + 8*lk;
            const short* aH   = (const short*)hbIn + (size_t)mrow*HID + 8*lk;
            const bf16x8* BL = (const bf16x8*)WcatL;
            f32x4 acc = {0.f,0.f,0.f,0.f};
            if (kh == 0){
                #pragma unroll 8
                for (int kt = 0; kt < 16; ++kt){
                    bf16x8 a = *(const bf16x8*)(aEmb + kt*32);
                    acc = __builtin_amdgcn_mfma_f32_16x16x32_bf16(a, BL[kt*64 + l], acc, 0,0,0);
                }
                #pragma unroll 8
                for (int kt = 16; kt < 56; ++kt){
                    bf16x8 a = *(const bf16x8*)(aGc + (kt-16)*32);
                    acc = __builtin_amdgcn_mfma_f32_16x16x32_bf16(a, BL[kt*64 + l], acc, 0,0,0);
                }
            } else {
                #pragma unroll 8
                for (int kt = 56; kt < 80; ++kt){
                    bf16x8 a = *(const bf16x8*)(aGc + (kt-16)*32);
                    acc = __builtin_amdgcn_mfma_f32_16x16x32_bf16(a, BL[kt*64 + l], acc, 0,0,0);
                }
                #pragma unroll 8
                for (int kt = 80; kt < 112; ++kt){
                    bf16x8 a = *(const bf16x8*)(aH + (kt-80)*32);
                    acc = __builtin_amdgcn_mfma_f32_16x16x32_bf16(a, BL[kt*64 + l], acc, 0,0,0);
                }
            }
            #pragma unroll
            for (int r=0; r<4; ++r) sh.gem.Dp[kh][16*rt + 4*lk + r][lm] = acc[r];
            __syncthreads();
            if (tid < 256){
                int j2 = tid & 63, du = tid >> 6;
                int u = 4*b + du;
                float g4[4];
                #pragma unroll
                for (int g=0; g<4; ++g){
                    int nl = 4*du + g;
                    g4[g] = sh.gem.Dp[0][j2][nl] + sh.gem.Dp[1][j2][nl] + p.bsum[16*b + nl];
                }
                float ig = sigm(g4[0]), fg = sigm(g4[1]), gg = tanhf(g4[2]), og = sigm(g4[3]);
                float cOld = p.cW[j2*HID + u];
                float cNew = fg*cOld + ig*gg;
                float hNew = og*tanhf(cNew);
                bool active = (t < sh.gem.lensL[j2]);
                float hOld = hFIn[j2*HID + u];
                float hKeep = active ? hNew : hOld;
                hFOut[j2*HID + u] = hKeep;
                hbOut[j2*HID + u] = __float2bfloat16(hKeep);
                p.cW[j2*HID + u] = active ? cNew : cOld;
                p.outH[((size_t)sh.gem.wLs[j2]*T + t)*HID + u] = active ? hNew : 0.f;
            }
        }
        grid.sync();
    }
}

extern "C" void kernel_launch(void* const* d_in, const int* in_sizes, int n_in,
                              void* d_out, int out_size, void* d_ws, size_t ws_size,
                              hipStream_t stream) {
    const float* img   = (const float*)d_in[0];
    const int*   sent  = (const int*)  d_in[1];
    const float* enc_h = (const float*)d_in[2];
    const float* enc_c = (const float*)d_in[3];
    const int*   lens  = (const int*)  d_in[4];
    const float* emb   = (const float*)d_in[5];
    const float* Wea   = (const float*)d_in[6];
    const float* bea   = (const float*)d_in[7];
    const float* Wda   = (const float*)d_in[8];
    const float* bda   = (const float*)d_in[9];
    const float* wfa   = (const float*)d_in[10];
    const float* bfa   = (const float*)d_in[11];
    const float* Wfb   = (const float*)d_in[12];
    const float* bfb   = (const float*)d_in[13];
    const float* Wih   = (const float*)d_in[14];
    const float* bih   = (const float*)d_in[15];
    const float* Whh   = (const float*)d_in[16];
    const float* bhh   = (const float*)d_in[17];

    float* outH = (float*)d_out;                       // [B,T,HID] f32
    float* outA = outH + (size_t)B*T*HID;              // [B,T,P]  f32

    char* wsb = (char*)d_ws;
    size_t off = 0;
    int* idxW  = (int*)(wsb + off); off += 256;
    int* rankW = (int*)(wsb + off); off += 256;
    __hip_bfloat16* att1w = (__hip_bfloat16*)(wsb + off); off += (size_t)B*P*ATT*2;       // 12.85MB
    __hip_bfloat16* img_s = (__hip_bfloat16*)(wsb + off); off += (size_t)B*P*ENC*2;       // 51.38MB
    __hip_bfloat16* emb_bf= (__hip_bfloat16*)(wsb + off); off += (size_t)10000*EMB*2;     // 10.24MB
    __hip_bfloat16* Wfrag = (__hip_bfloat16*)(wsb + off); off += (size_t)4*HID*KTOT*2;    // 29.36MB
    __hip_bfloat16* W2    = (__hip_bfloat16*)(wsb + off); off += (size_t)N2*HID*2;        // 5.24MB
    __hip_bfloat16* Wea_bf= (__hip_bfloat16*)(wsb + off); off += (size_t)ATT*ENC*2;       // 2.10MB (prologue-only)
    float* bsum  = (float*)(wsb + off); off += 4*HID*4;
    float* bias2 = (float*)(wsb + off); off += N2*4;
    float* hA    = (float*)(wsb + off); off += B*HID*4;
    float* hB    = (float*)(wsb + off); off += B*HID*4;
    float* cWs   = (float*)(wsb + off); off += B*HID*4;
    __hip_bfloat16* hbfA = (__hip_bfloat16*)(wsb + off); off += B*HID*2;
    __hip_bfloat16* hbfB = (__hip_bfloat16*)(wsb + off); off += B*HID*2;
    float* D2    = (float*)(wsb + off); off += (size_t)B*N2*4;
    __hip_bfloat16* gcW  = (__hip_bfloat16*)(wsb + off); off += B*ENC*2;
    float* ePW   = (float*)Wea_bf;   // overlay: eP (200KB) lives in Wea_bf's space, used only in k_scan

    k_sort<<<1, 64, 0, stream>>>(lens, idxW, rankW);
    k_init_hc<<<B, 256, 0, stream>>>(enc_h, enc_c, idxW, hA, cWs, hbfA);
    k_cvt_wcat<<<57344, 256, 0, stream>>>(Wih, Whh, Wfrag);
    k_bsum<<<16, 256, 0, stream>>>(bih, bhh, bsum);
    k_cvt_w2<<<N2, 256, 0, stream>>>(Wda, bda, Wfb, bfb, W2, bias2);
    k_cvt_emb<<<20000, 256, 0, stream>>>(emb, emb_bf);
    k_cvt_wea<<<ATT, 256, 0, stream>>>(Wea, Wea_bf);
    k_cvt_img<<<dim3(P*ENC/256, B), 256, 0, stream>>>(img, idxW, img_s);
    k_att1m<<<dim3((B*P)/64, ATT/64), 256, 0, stream>>>(img_s, Wea_bf, bea, att1w);

    SP sp;
    sp.att1w = att1w; sp.img_s = img_s; sp.emb_bf = emb_bf; sp.Wfrag = Wfrag; sp.W2 = W2;
    sp.bsum = bsum; sp.bias2 = bias2; sp.wfa = wfa; sp.bfa = bfa;
    sp.sent = sent; sp.idx = idxW; sp.rank = rankW; sp.lens = lens;
    sp.D2 = D2; sp.eP = ePW; sp.gc = gcW;
    sp.hF0 = hA; sp.hF1 = hB; sp.cW = cWs;
    sp.hb0 = hbfA; sp.hb1 = hbfB;
    sp.outH = outH; sp.outA = outA;

    void* args[] = { &sp };
    hipLaunchCooperativeKernel(reinterpret_cast<void*>(k_scan), dim3(256), dim3(512),
                               args, 0, stream);
}

// Round 7
// 18855.687 us; speedup vs baseline: 2.5237x; 1.3544x over previous
//
#include <hip/hip_runtime.h>
#include <hip/hip_bf16.h>
#include <math.h>

#define B 64
#define T 160
#define P 196
#define ENC 2048
#define ATT 512
#define EMB 512
#define HID 1024
#define KTOT 3584   // EMB + ENC + HID
#define N2 2560     // ATT + ENC
#define KT4 112     // KTOT/32
#define NTHR 512
#define NBLK 256

typedef __attribute__((ext_vector_type(8))) short bf16x8;
typedef __attribute__((ext_vector_type(4))) float f32x4;

__device__ __forceinline__ float sigm(float x){ return 1.0f/(1.0f+__expf(-x)); }
__device__ __forceinline__ float bfu(short s){ return __uint_as_float(((unsigned)(unsigned short)s) << 16); }

// fast grid barrier: monotone counter, one atomic add per block per barrier.
// Caller passes the barrier ordinal k (0,1,2,...); spin until count >= (k+1)*NBLK.
__device__ __forceinline__ void gbar(unsigned* cnt, unsigned k){
    __syncthreads();
    if (threadIdx.x == 0){
        __threadfence();   // release our writes to device scope
        __hip_atomic_fetch_add(cnt, 1u, __ATOMIC_RELAXED, __HIP_MEMORY_SCOPE_AGENT);
        unsigned target = (k + 1u)*NBLK;
        while (__hip_atomic_load(cnt, __ATOMIC_RELAXED, __HIP_MEMORY_SCOPE_AGENT) < target){
            __builtin_amdgcn_s_sleep(2);
        }
        __threadfence();   // acquire: invalidate stale caches before readers proceed
    }
    __syncthreads();
}

// ---------- sort: stable descending by lens ----------
__global__ void k_sort(const int* lens, int* idx, int* rank, unsigned* barCnt){
    __shared__ int L[B];
    int i = threadIdx.x;
    L[i] = lens[i];
    if (i == 0) *barCnt = 0u;
    __syncthreads();
    int li = L[i];
    int r = 0;
    for (int j = 0; j < B; ++j){
        int lj = L[j];
        if (lj > li || (lj == li && j < i)) r++;
    }
    rank[i] = r;
    idx[r] = i;
}

// ---------- init h0/c0 (sorted order) + bf16 copy ----------
__global__ void k_init_hc(const float* enc_h, const float* enc_c, const int* idx,
                          float* h, float* c, __hip_bfloat16* h_bf){
    int j = blockIdx.x;
    int o = idx[j];
    for (int k = threadIdx.x; k < HID; k += blockDim.x){
        float hv = (k < 512) ? enc_h[o*512 + k] : enc_h[B*512 + o*512 + (k-512)];
        float cv = (k < 512) ? enc_c[o*512 + k] : enc_c[B*512 + o*512 + (k-512)];
        h[j*HID + k] = hv;
        c[j*HID + k] = cv;
        h_bf[j*HID + k] = __float2bfloat16(hv);
    }
}

// ---------- Wcat in per-strip MFMA-fragment order (once) ----------
__global__ void k_cvt_wcat(const float* Wih, const float* Whh, __hip_bfloat16* Wfrag){
    size_t i = (size_t)blockIdx.x*256 + threadIdx.x;   // 57,344 blocks -> 14,680,064
    int e = (int)(i & 7);
    size_t t2 = i >> 3;
    int lane = (int)(t2 & 63);
    size_t t3 = t2 >> 6;
    int kt = (int)(t3 % KT4);
    int strip = (int)(t3 / KT4);
    int n = strip*16 + (lane & 15);
    int r = (n & 3)*HID + (n >> 2);
    int k = kt*32 + (lane >> 4)*8 + e;
    float v = (k < EMB+ENC) ? Wih[(size_t)r*(EMB+ENC) + k]
                            : Whh[(size_t)r*HID + (k - EMB - ENC)];
    Wfrag[i] = __float2bfloat16(v);
}

__global__ void k_bsum(const float* bih, const float* bhh, float* bsum){
    int n = blockIdx.x*256 + threadIdx.x;
    int r = (n & 3)*HID + (n >> 2);
    bsum[n] = bih[r] + bhh[r];
}

__global__ void k_cvt_w2(const float* Wda, const float* bda, const float* Wfb, const float* bfb,
                         __hip_bfloat16* W2, float* bias2){
    int n = blockIdx.x;              // 0..2559
    const float* src = (n < ATT) ? (Wda + (size_t)n*HID) : (Wfb + (size_t)(n-ATT)*HID);
    __hip_bfloat16* dst = W2 + (size_t)n*HID;
    for (int k = threadIdx.x; k < HID; k += 256) dst[k] = __float2bfloat16(src[k]);
    if (threadIdx.x == 0) bias2[n] = (n < ATT) ? bda[n] : bfb[n-ATT];
}

__global__ void k_cvt_emb(const float* emb, __hip_bfloat16* emb_bf){
    size_t i = (size_t)blockIdx.x*256 + threadIdx.x;
    emb_bf[i] = __float2bfloat16(emb[i]);
}

__global__ void k_cvt_wea(const float* Wea, __hip_bfloat16* Wea_bf){
    int n = blockIdx.x;
    for (int k = threadIdx.x; k < ENC; k += 256)
        Wea_bf[(size_t)n*ENC + k] = __float2bfloat16(Wea[(size_t)n*ENC + k]);
}

__global__ void k_cvt_img(const float* img, const int* idx, __hip_bfloat16* img_s){
    int j = blockIdx.y;
    int o = idx[j];
    size_t off = (size_t)blockIdx.x*256 + threadIdx.x;
    img_s[(size_t)j*P*ENC + off] = __float2bfloat16(img[(size_t)o*P*ENC + off]);
}

// ---------- att1 (once, MFMA) ----------
__global__ __launch_bounds__(256) void k_att1m(const __hip_bfloat16* img_s, const __hip_bfloat16* Wea_bf,
                                               const float* bea, __hip_bfloat16* att1w){
    int m0 = blockIdx.x * 64, n0 = blockIdx.y * 64;
    int tid = threadIdx.x, w = tid >> 6, l = tid & 63, lm = l & 15, lk = l >> 4;
    const short* ap = (const short*)img_s + (size_t)(m0 + 16*w + lm)*ENC + 8*lk;
    const short* bp = (const short*)Wea_bf + (size_t)(n0 + lm)*ENC + 8*lk;
    f32x4 acc[4];
    #pragma unroll
    for (int nt=0; nt<4; ++nt) acc[nt] = (f32x4){0.f,0.f,0.f,0.f};
    #pragma unroll 4
    for (int kt = 0; kt < ENC/32; ++kt){
        bf16x8 a = *(const bf16x8*)(ap + kt*32);
        #pragma unroll
        for (int nt=0; nt<4; ++nt){
            bf16x8 bb = *(const bf16x8*)(bp + (size_t)nt*16*ENC + kt*32);
            acc[nt] = __builtin_amdgcn_mfma_f32_16x16x32_bf16(a, bb, acc[nt], 0,0,0);
        }
    }
    #pragma unroll
    for (int nt=0; nt<4; ++nt){
        int n = n0 + nt*16 + lm;
        float bv = bea[n];
        #pragma unroll
        for (int r=0; r<4; ++r){
            int m = m0 + 16*w + 4*lk + r;
            att1w[(size_t)m*ATT + n] = __float2bfloat16(acc[nt][r] + bv);
        }
    }
}

// ---------- persistent cooperative scan ----------
struct SP {
    const __hip_bfloat16 *att1w, *img_s, *emb_bf, *Wfrag, *W2;
    const float *bsum, *bias2, *wfa, *bfa;
    const int *sent, *idx, *rank, *lens;
    float *D2;
    __hip_bfloat16 *gc;
    float *hF0, *hF1, *cW;
    __hip_bfloat16 *hb0, *hb1;
    float *outH, *outA;
    unsigned *barCnt;
};

__global__ __launch_bounds__(512) void k_scan(SP p){
    __shared__ short WcatL[KT4*64*8];          // 114,688 B, fragment-ordered
    __shared__ union {
        struct { float Dp[2][64][17]; int tokL[64], lensL[64], wLs[64]; } gem;
        struct { float att2L[512]; float wfaL[512]; float red[512]; float aL[200]; float ctxP[4][512]; } p23;
    } sh;

    int b = blockIdx.x, tid = threadIdx.x;
    int w = tid >> 6, l = tid & 63, lm = l & 15, lk = l >> 4;
    unsigned bk = 0;

    // one-time LDS fill (straight copy, frag order)
    {
        const bf16x8* src = (const bf16x8*)((const short*)p.Wfrag + (size_t)b*KT4*64*8);
        bf16x8* dst = (bf16x8*)WcatL;
        #pragma unroll
        for (int i = 0; i < KT4*64/NTHR; ++i) dst[tid + i*NTHR] = src[tid + i*NTHR];
    }
    __syncthreads();

    float bfa0 = p.bfa[0];

    for (int t = 0; t < T; ++t){
        const __hip_bfloat16* hbIn = (t & 1) ? p.hb1 : p.hb0;
        __hip_bfloat16*       hbOut = (t & 1) ? p.hb0 : p.hb1;
        const float* hFIn = (t & 1) ? p.hF1 : p.hF0;
        float*       hFOut = (t & 1) ? p.hF0 : p.hF1;

        // ---- P1: D2[64][2560] = h_bf @ W2^T + bias2 ; blocks < 160, K-split waves ----
        if (b < N2/16){
            int n0 = b*16;
            int rt = w & 3, kh = w >> 2;
            const short* ap = (const short*)hbIn + (size_t)(16*rt + lm)*HID + kh*512 + 8*lk;
            const short* bp = (const short*)p.W2 + (size_t)(n0 + lm)*HID + kh*512 + 8*lk;
            f32x4 acc = {0.f,0.f,0.f,0.f};
            #pragma unroll 8
            for (int kt = 0; kt < 16; ++kt){
                bf16x8 a = *(const bf16x8*)(ap + kt*32);
                bf16x8 bb = *(const bf16x8*)(bp + kt*32);
                acc = __builtin_amdgcn_mfma_f32_16x16x32_bf16(a, bb, acc, 0,0,0);
            }
            #pragma unroll
            for (int r=0; r<4; ++r) sh.gem.Dp[kh][16*rt + 4*lk + r][lm] = acc[r];
            __syncthreads();
            #pragma unroll
            for (int e2=0; e2<2; ++e2){
                int ii = tid + e2*512;
                int m = ii >> 4, nl = ii & 15;
                p.D2[m*N2 + n0 + nl] = sh.gem.Dp[0][m][nl] + sh.gem.Dp[1][m][nl] + p.bias2[n0 + nl];
            }
        }
        gbar(p.barCnt, bk++);

        // ---- P23: e + softmax + context + gc ; block = (j=b&63, q=b>>6) ----
        {
            int j = b & 63, q = b >> 6;
            int o = p.idx[j], wj = p.rank[j], lj = p.lens[o];

            sh.p23.att2L[tid] = p.D2[j*N2 + tid];
            sh.p23.wfaL[tid]  = p.wfa[tid];
            __syncthreads();

            int pp = tid & 255, ah = tid >> 8;
            float acc = 0.f;
            if (pp < P){
                const short* ar = (const short*)p.att1w + (size_t)(j*P + pp)*ATT + ah*256;
                #pragma unroll 8
                for (int k8 = 0; k8 < 32; ++k8){
                    bf16x8 v = *(const bf16x8*)(ar + k8*8);
                    #pragma unroll
                    for (int z=0; z<8; ++z){
                        int a = ah*256 + k8*8 + z;
                        acc += fmaxf(bfu(v[z]) + sh.p23.att2L[a], 0.f) * sh.p23.wfaL[a];
                    }
                }
            }
            sh.p23.red[tid] = acc;
            __syncthreads();
            float e = -1e30f;
            if (tid < P) e = sh.p23.red[tid] + sh.p23.red[tid + 256] + bfa0;
            __syncthreads();
            sh.p23.red[tid] = (tid < P) ? e : -1e30f;
            __syncthreads();
            for (int s = 256; s > 0; s >>= 1){
                if (tid < s) sh.p23.red[tid] = fmaxf(sh.p23.red[tid], sh.p23.red[tid+s]);
                __syncthreads();
            }
            float m = sh.p23.red[0];
            __syncthreads();
            float ex = (tid < P) ? __expf(e - m) : 0.f;
            sh.p23.red[tid] = ex;
            __syncthreads();
            for (int s = 256; s > 0; s >>= 1){
                if (tid < s) sh.p23.red[tid] += sh.p23.red[tid+s];
                __syncthreads();
            }
            float ssum = sh.p23.red[0];
            if (tid < P){
                float alpha = ex / ssum;
                sh.p23.aL[tid] = alpha;
                if (q == 0) p.outA[((size_t)(wj*T + t))*P + tid] = (t < lj) ? alpha : 0.f;
            }
            if (tid >= P && tid < 200) sh.p23.aL[tid] = 0.f;
            __syncthreads();

            // context quarter [q*512, q*512+512): wave w takes p = w, w+8, ...
            const short* ib = (const short*)p.img_s + (size_t)j*P*ENC + q*512 + l*8;
            float a8[8];
            #pragma unroll
            for (int z=0; z<8; ++z) a8[z] = 0.f;
            #pragma unroll 5
            for (int i = 0; i < 25; ++i){
                int pp2 = w + 8*i;
                bf16x8 v = *(const bf16x8*)(ib + (size_t)pp2*ENC);
                float al = sh.p23.aL[pp2];
                #pragma unroll
                for (int z=0; z<8; ++z) a8[z] += al * bfu(v[z]);
            }
            if (w < 4){
                #pragma unroll
                for (int z=0; z<8; ++z) sh.p23.ctxP[w][l*8+z] = a8[z];
            }
            __syncthreads();
            if (w >= 4){
                #pragma unroll
                for (int z=0; z<8; ++z) sh.p23.ctxP[w-4][l*8+z] += a8[z];
            }
            __syncthreads();
            {
                int d = tid;
                float ctx = sh.p23.ctxP[0][d] + sh.p23.ctxP[1][d] + sh.p23.ctxP[2][d] + sh.p23.ctxP[3][d];
                int eg = q*512 + d;
                float gate = sigm(p.D2[j*N2 + ATT + eg]);
                p.gc[j*ENC + eg] = __float2bfloat16(gate*ctx);
            }
        }
        gbar(p.barCnt, bk++);

        // ---- P4: gates GEMM (K-split waves, B from LDS) + LSTM + outputs ----
        {
            if (tid < 64){
                int o = p.idx[tid];
                sh.gem.tokL[tid] = p.sent[o*T + t];
                sh.gem.lensL[tid] = p.lens[o];
                sh.gem.wLs[tid] = p.rank[tid];
            }
            __syncthreads();
            int rt = w & 3, kh = w >> 2;
            int mrow = 16*rt + lm;
            int tok = sh.gem.tokL[mrow];
            const short* aEmb = (const short*)p.emb_bf + (size_t)tok*EMB + 8*lk;
            const short* aGc  = (const short*)p.gc + (size_t)mrow*ENC + 8*lk;
            const short* aH   = (const short*)hbIn + (size_t)mrow*HID + 8*lk;
            const bf16x8* BL = (const bf16x8*)WcatL;
            f32x4 acc = {0.f,0.f,0.f,0.f};
            if (kh == 0){
                #pragma unroll 8
                for (int kt = 0; kt < 16; ++kt){
                    bf16x8 a = *(const bf16x8*)(aEmb + kt*32);
                    acc = __builtin_amdgcn_mfma_f32_16x16x32_bf16(a, BL[kt*64 + l], acc, 0,0,0);
                }
                #pragma unroll 8
                for (int kt = 16; kt < 56; ++kt){
                    bf16x8 a = *(const bf16x8*)(aGc + (kt-16)*32);
                    acc = __builtin_amdgcn_mfma_f32_16x16x32_bf16(a, BL[kt*64 + l], acc, 0,0,0);
                }
            } else {
                #pragma unroll 8
                for (int kt = 56; kt < 80; ++kt){
                    bf16x8 a = *(const bf16x8*)(aGc + (kt-16)*32);
                    acc = __builtin_amdgcn_mfma_f32_16x16x32_bf16(a, BL[kt*64 + l], acc, 0,0,0);
                }
                #pragma unroll 8
                for (int kt = 80; kt < 112; ++kt){
                    bf16x8 a = *(const bf16x8*)(aH + (kt-80)*32);
                    acc = __builtin_amdgcn_mfma_f32_16x16x32_bf16(a, BL[kt*64 + l], acc, 0,0,0);
                }
            }
            #pragma unroll
            for (int r=0; r<4; ++r) sh.gem.Dp[kh][16*rt + 4*lk + r][lm] = acc[r];
            __syncthreads();
            if (tid < 256){
                int j2 = tid & 63, du = tid >> 6;
                int u = 4*b + du;
                float g4[4];
                #pragma unroll
                for (int g=0; g<4; ++g){
                    int nl = 4*du + g;
                    g4[g] = sh.gem.Dp[0][j2][nl] + sh.gem.Dp[1][j2][nl] + p.bsum[16*b + nl];
                }
                float ig = sigm(g4[0]), fg = sigm(g4[1]), gg = tanhf(g4[2]), og = sigm(g4[3]);
                float cOld = p.cW[j2*HID + u];
                float cNew = fg*cOld + ig*gg;
                float hNew = og*tanhf(cNew);
                bool active = (t < sh.gem.lensL[j2]);
                float hOld = hFIn[j2*HID + u];
                float hKeep = active ? hNew : hOld;
                hFOut[j2*HID + u] = hKeep;
                hbOut[j2*HID + u] = __float2bfloat16(hKeep);
                p.cW[j2*HID + u] = active ? cNew : cOld;
                p.outH[((size_t)sh.gem.wLs[j2]*T + t)*HID + u] = active ? hNew : 0.f;
            }
        }
        gbar(p.barCnt, bk++);
    }
}

extern "C" void kernel_launch(void* const* d_in, const int* in_sizes, int n_in,
                              void* d_out, int out_size, void* d_ws, size_t ws_size,
                              hipStream_t stream) {
    const float* img   = (const float*)d_in[0];
    const int*   sent  = (const int*)  d_in[1];
    const float* enc_h = (const float*)d_in[2];
    const float* enc_c = (const float*)d_in[3];
    const int*   lens  = (const int*)  d_in[4];
    const float* emb   = (const float*)d_in[5];
    const float* Wea   = (const float*)d_in[6];
    const float* bea   = (const float*)d_in[7];
    const float* Wda   = (const float*)d_in[8];
    const float* bda   = (const float*)d_in[9];
    const float* wfa   = (const float*)d_in[10];
    const float* bfa   = (const float*)d_in[11];
    const float* Wfb   = (const float*)d_in[12];
    const float* bfb   = (const float*)d_in[13];
    const float* Wih   = (const float*)d_in[14];
    const float* bih   = (const float*)d_in[15];
    const float* Whh   = (const float*)d_in[16];
    const float* bhh   = (const float*)d_in[17];

    float* outH = (float*)d_out;                       // [B,T,HID] f32
    float* outA = outH + (size_t)B*T*HID;              // [B,T,P]  f32

    char* wsb = (char*)d_ws;
    size_t off = 0;
    int* idxW  = (int*)(wsb + off); off += 256;
    int* rankW = (int*)(wsb + off); off += 256;
    unsigned* barCnt = (unsigned*)(wsb + off); off += 256;
    __hip_bfloat16* att1w = (__hip_bfloat16*)(wsb + off); off += (size_t)B*P*ATT*2;       // 12.85MB
    __hip_bfloat16* img_s = (__hip_bfloat16*)(wsb + off); off += (size_t)B*P*ENC*2;       // 51.38MB
    __hip_bfloat16* emb_bf= (__hip_bfloat16*)(wsb + off); off += (size_t)10000*EMB*2;     // 10.24MB
    __hip_bfloat16* Wfrag = (__hip_bfloat16*)(wsb + off); off += (size_t)4*HID*KTOT*2;    // 29.36MB
    __hip_bfloat16* W2    = (__hip_bfloat16*)(wsb + off); off += (size_t)N2*HID*2;        // 5.24MB
    __hip_bfloat16* Wea_bf= (__hip_bfloat16*)(wsb + off); off += (size_t)ATT*ENC*2;       // 2.10MB (prologue-only)
    float* bsum  = (float*)(wsb + off); off += 4*HID*4;
    float* bias2 = (float*)(wsb + off); off += N2*4;
    float* hA    = (float*)(wsb + off); off += B*HID*4;
    float* hB    = (float*)(wsb + off); off += B*HID*4;
    float* cWs   = (float*)(wsb + off); off += B*HID*4;
    __hip_bfloat16* hbfA = (__hip_bfloat16*)(wsb + off); off += B*HID*2;
    __hip_bfloat16* hbfB = (__hip_bfloat16*)(wsb + off); off += B*HID*2;
    float* D2    = (float*)(wsb + off); off += (size_t)B*N2*4;
    __hip_bfloat16* gcW  = (__hip_bfloat16*)(wsb + off); off += B*ENC*2;

    k_sort<<<1, 64, 0, stream>>>(lens, idxW, rankW, barCnt);
    k_init_hc<<<B, 256, 0, stream>>>(enc_h, enc_c, idxW, hA, cWs, hbfA);
    k_cvt_wcat<<<57344, 256, 0, stream>>>(Wih, Whh, Wfrag);
    k_bsum<<<16, 256, 0, stream>>>(bih, bhh, bsum);
    k_cvt_w2<<<N2, 256, 0, stream>>>(Wda, bda, Wfb, bfb, W2, bias2);
    k_cvt_emb<<<20000, 256, 0, stream>>>(emb, emb_bf);
    k_cvt_wea<<<ATT, 256, 0, stream>>>(Wea, Wea_bf);
    k_cvt_img<<<dim3(P*ENC/256, B), 256, 0, stream>>>(img, idxW, img_s);
    k_att1m<<<dim3((B*P)/64, ATT/64), 256, 0, stream>>>(img_s, Wea_bf, bea, att1w);

    SP sp;
    sp.att1w = att1w; sp.img_s = img_s; sp.emb_bf = emb_bf; sp.Wfrag = Wfrag; sp.W2 = W2;
    sp.bsum = bsum; sp.bias2 = bias2; sp.wfa = wfa; sp.bfa = bfa;
    sp.sent = sent; sp.idx = idxW; sp.rank = rankW; sp.lens = lens;
    sp.D2 = D2; sp.gc = gcW;
    sp.hF0 = hA; sp.hF1 = hB; sp.cW = cWs;
    sp.hb0 = hbfA; sp.hb1 = hbfB;
    sp.outH = outH; sp.outA = outA;
    sp.barCnt = barCnt;

    void* args[] = { &sp };
    hipLaunchCooperativeKernel(reinterpret_cast<void*>(k_scan), dim3(NBLK), dim3(NTHR),
                               args, 0, stream);
}

// Round 8
// 14052.119 us; speedup vs baseline: 3.3864x; 1.3418x over previous
//
#include <hip/hip_runtime.h>
#include <hip/hip_bf16.h>
#include <math.h>

#define B 64
#define T 160
#define P 196
#define ENC 2048
#define ATT 512
#define EMB 512
#define HID 1024
#define KTOT 3584   // EMB + ENC + HID
#define N2 2560     // ATT + ENC
#define KT4 112     // KTOT/32
#define NTHR 512
#define NBLK 256
#define NGRP 8
#define GRPSZ (NBLK/NGRP)

typedef __attribute__((ext_vector_type(8))) short bf16x8;
typedef __attribute__((ext_vector_type(4))) float f32x4;

__device__ __forceinline__ float sigm(float x){ return 1.0f/(1.0f+__expf(-x)); }
__device__ __forceinline__ float bfu(short s){ return __uint_as_float(((unsigned)(unsigned short)s) << 16); }

// hierarchical grid barrier: 8 group counters (1KB apart) + top counter.
// group g = blockIdx.x & 7 (32 blocks/group). Monotone counters, round k.
__device__ __forceinline__ void gbar(unsigned* bar, unsigned k){
    __syncthreads();
    if (threadIdx.x == 0){
        __threadfence();                                   // release our writes
        unsigned g = blockIdx.x & (NGRP-1);
        unsigned* gcnt = bar + g*256;                      // 1KB apart
        unsigned* top  = bar + NGRP*256;
        unsigned old = __hip_atomic_fetch_add(gcnt, 1u, __ATOMIC_RELAXED, __HIP_MEMORY_SCOPE_AGENT);
        if (old == (k + 1u)*GRPSZ - 1u){                   // last in group this round
            __threadfence();
            __hip_atomic_fetch_add(top, 1u, __ATOMIC_RELAXED, __HIP_MEMORY_SCOPE_AGENT);
        }
        unsigned target = (k + 1u)*NGRP;
        while (__hip_atomic_load(top, __ATOMIC_RELAXED, __HIP_MEMORY_SCOPE_AGENT) < target){
            __builtin_amdgcn_s_sleep(2);
        }
        __threadfence();                                   // acquire
    }
    __syncthreads();
}

// ---------- sort: stable descending by lens ----------
__global__ void k_sort(const int* lens, int* idx, int* rank, unsigned* barCnt){
    __shared__ int L[B];
    int i = threadIdx.x;
    L[i] = lens[i];
    if (i <= NGRP) barCnt[i*256] = 0u;     // 8 group counters + top
    __syncthreads();
    int li = L[i];
    int r = 0;
    for (int j = 0; j < B; ++j){
        int lj = L[j];
        if (lj > li || (lj == li && j < i)) r++;
    }
    rank[i] = r;
    idx[r] = i;
}

// ---------- init h0/c0 (sorted order) + bf16 copy ----------
__global__ void k_init_hc(const float* enc_h, const float* enc_c, const int* idx,
                          float* h, float* c, __hip_bfloat16* h_bf){
    int j = blockIdx.x;
    int o = idx[j];
    for (int k = threadIdx.x; k < HID; k += blockDim.x){
        float hv = (k < 512) ? enc_h[o*512 + k] : enc_h[B*512 + o*512 + (k-512)];
        float cv = (k < 512) ? enc_c[o*512 + k] : enc_c[B*512 + o*512 + (k-512)];
        h[j*HID + k] = hv;
        c[j*HID + k] = cv;
        h_bf[j*HID + k] = __float2bfloat16(hv);
    }
}

// ---------- Wcat in per-strip MFMA-fragment order (once) ----------
__global__ void k_cvt_wcat(const float* Wih, const float* Whh, __hip_bfloat16* Wfrag){
    size_t i = (size_t)blockIdx.x*256 + threadIdx.x;   // 57,344 blocks -> 14,680,064
    int e = (int)(i & 7);
    size_t t2 = i >> 3;
    int lane = (int)(t2 & 63);
    size_t t3 = t2 >> 6;
    int kt = (int)(t3 % KT4);
    int strip = (int)(t3 / KT4);
    int n = strip*16 + (lane & 15);
    int r = (n & 3)*HID + (n >> 2);
    int k = kt*32 + (lane >> 4)*8 + e;
    float v = (k < EMB+ENC) ? Wih[(size_t)r*(EMB+ENC) + k]
                            : Whh[(size_t)r*HID + (k - EMB - ENC)];
    Wfrag[i] = __float2bfloat16(v);
}

__global__ void k_bsum(const float* bih, const float* bhh, float* bsum){
    int n = blockIdx.x*256 + threadIdx.x;
    int r = (n & 3)*HID + (n >> 2);
    bsum[n] = bih[r] + bhh[r];
}

__global__ void k_cvt_w2(const float* Wda, const float* bda, const float* Wfb, const float* bfb,
                         __hip_bfloat16* W2, float* bias2){
    int n = blockIdx.x;              // 0..2559
    const float* src = (n < ATT) ? (Wda + (size_t)n*HID) : (Wfb + (size_t)(n-ATT)*HID);
    __hip_bfloat16* dst = W2 + (size_t)n*HID;
    for (int k = threadIdx.x; k < HID; k += 256) dst[k] = __float2bfloat16(src[k]);
    if (threadIdx.x == 0) bias2[n] = (n < ATT) ? bda[n] : bfb[n-ATT];
}

__global__ void k_cvt_emb(const float* emb, __hip_bfloat16* emb_bf){
    size_t i = (size_t)blockIdx.x*256 + threadIdx.x;
    emb_bf[i] = __float2bfloat16(emb[i]);
}

__global__ void k_cvt_wea(const float* Wea, __hip_bfloat16* Wea_bf){
    int n = blockIdx.x;
    for (int k = threadIdx.x; k < ENC; k += 256)
        Wea_bf[(size_t)n*ENC + k] = __float2bfloat16(Wea[(size_t)n*ENC + k]);
}

__global__ void k_cvt_img(const float* img, const int* idx, __hip_bfloat16* img_s){
    int j = blockIdx.y;
    int o = idx[j];
    size_t off = (size_t)blockIdx.x*256 + threadIdx.x;
    img_s[(size_t)j*P*ENC + off] = __float2bfloat16(img[(size_t)o*P*ENC + off]);
}

// ---------- att1 (once, MFMA) ----------
__global__ __launch_bounds__(256) void k_att1m(const __hip_bfloat16* img_s, const __hip_bfloat16* Wea_bf,
                                               const float* bea, __hip_bfloat16* att1w){
    int m0 = blockIdx.x * 64, n0 = blockIdx.y * 64;
    int tid = threadIdx.x, w = tid >> 6, l = tid & 63, lm = l & 15, lk = l >> 4;
    const short* ap = (const short*)img_s + (size_t)(m0 + 16*w + lm)*ENC + 8*lk;
    const short* bp = (const short*)Wea_bf + (size_t)(n0 + lm)*ENC + 8*lk;
    f32x4 acc[4];
    #pragma unroll
    for (int nt=0; nt<4; ++nt) acc[nt] = (f32x4){0.f,0.f,0.f,0.f};
    #pragma unroll 4
    for (int kt = 0; kt < ENC/32; ++kt){
        bf16x8 a = *(const bf16x8*)(ap + kt*32);
        #pragma unroll
        for (int nt=0; nt<4; ++nt){
            bf16x8 bb = *(const bf16x8*)(bp + (size_t)nt*16*ENC + kt*32);
            acc[nt] = __builtin_amdgcn_mfma_f32_16x16x32_bf16(a, bb, acc[nt], 0,0,0);
        }
    }
    #pragma unroll
    for (int nt=0; nt<4; ++nt){
        int n = n0 + nt*16 + lm;
        float bv = bea[n];
        #pragma unroll
        for (int r=0; r<4; ++r){
            int m = m0 + 16*w + 4*lk + r;
            att1w[(size_t)m*ATT + n] = __float2bfloat16(acc[nt][r] + bv);
        }
    }
}

// ---------- persistent cooperative scan ----------
struct SP {
    const __hip_bfloat16 *att1w, *img_s, *emb_bf, *Wfrag, *W2;
    const float *bsum, *bias2, *wfa, *bfa;
    const int *sent, *idx, *rank, *lens;
    float *D2;
    __hip_bfloat16 *gc;
    float *hF0, *hF1, *cW;
    __hip_bfloat16 *hb0, *hb1;
    float *outH, *outA;
    unsigned *barCnt;
};

__global__ __launch_bounds__(512) void k_scan(SP p){
    __shared__ short WcatL[KT4*64*8];          // 114,688 B, fragment-ordered
    __shared__ union {
        struct { float Dp[2][64][17]; int tokL[64], lensL[64], wLs[64]; } gem;
        struct { float att2L[512]; float wfaL[512]; float red[512]; float aL[200]; float ctxP[4][512]; } p23;
    } sh;

    int b = blockIdx.x, tid = threadIdx.x;
    int w = tid >> 6, l = tid & 63, lm = l & 15, lk = l >> 4;
    unsigned bk = 0;

    // one-time LDS fill (straight copy, frag order)
    {
        const bf16x8* src = (const bf16x8*)((const short*)p.Wfrag + (size_t)b*KT4*64*8);
        bf16x8* dst = (bf16x8*)WcatL;
        #pragma unroll
        for (int i = 0; i < KT4*64/NTHR; ++i) dst[tid + i*NTHR] = src[tid + i*NTHR];
    }
    __syncthreads();

    float bfa0 = p.bfa[0];

    for (int t = 0; t < T; ++t){
        const __hip_bfloat16* hbIn = (t & 1) ? p.hb1 : p.hb0;
        __hip_bfloat16*       hbOut = (t & 1) ? p.hb0 : p.hb1;
        const float* hFIn = (t & 1) ? p.hF1 : p.hF0;
        float*       hFOut = (t & 1) ? p.hF0 : p.hF1;

        // ---- P1: D2[64][2560] = h_bf @ W2^T + bias2 ; blocks < 160, K-split waves ----
        if (b < N2/16){
            int n0 = b*16;
            int rt = w & 3, kh = w >> 2;
            const short* ap = (const short*)hbIn + (size_t)(16*rt + lm)*HID + kh*512 + 8*lk;
            const short* bp = (const short*)p.W2 + (size_t)(n0 + lm)*HID + kh*512 + 8*lk;
            f32x4 acc = {0.f,0.f,0.f,0.f};
            #pragma unroll 8
            for (int kt = 0; kt < 16; ++kt){
                bf16x8 a = *(const bf16x8*)(ap + kt*32);
                bf16x8 bb = *(const bf16x8*)(bp + kt*32);
                acc = __builtin_amdgcn_mfma_f32_16x16x32_bf16(a, bb, acc, 0,0,0);
            }
            #pragma unroll
            for (int r=0; r<4; ++r) sh.gem.Dp[kh][16*rt + 4*lk + r][lm] = acc[r];
            __syncthreads();
            #pragma unroll
            for (int e2=0; e2<2; ++e2){
                int ii = tid + e2*512;
                int m = ii >> 4, nl = ii & 15;
                p.D2[m*N2 + n0 + nl] = sh.gem.Dp[0][m][nl] + sh.gem.Dp[1][m][nl] + p.bias2[n0 + nl];
            }
        }
        gbar(p.barCnt, bk++);

        // ---- P23: e + softmax + context + gc ; block = (j=b&63, q=b>>6) ----
        {
            int j = b & 63, q = b >> 6;
            int o = p.idx[j], wj = p.rank[j], lj = p.lens[o];

            sh.p23.att2L[tid] = p.D2[j*N2 + tid];
            sh.p23.wfaL[tid]  = p.wfa[tid];
            __syncthreads();

            int pp = tid & 255, ah = tid >> 8;
            float acc = 0.f;
            if (pp < P){
                const short* ar = (const short*)p.att1w + (size_t)(j*P + pp)*ATT + ah*256;
                #pragma unroll 8
                for (int k8 = 0; k8 < 32; ++k8){
                    bf16x8 v = *(const bf16x8*)(ar + k8*8);
                    #pragma unroll
                    for (int z=0; z<8; ++z){
                        int a = ah*256 + k8*8 + z;
                        acc += fmaxf(bfu(v[z]) + sh.p23.att2L[a], 0.f) * sh.p23.wfaL[a];
                    }
                }
            }
            sh.p23.red[tid] = acc;
            __syncthreads();
            float e = -1e30f;
            if (tid < P) e = sh.p23.red[tid] + sh.p23.red[tid + 256] + bfa0;
            __syncthreads();
            sh.p23.red[tid] = (tid < P) ? e : -1e30f;
            __syncthreads();
            for (int s = 256; s > 0; s >>= 1){
                if (tid < s) sh.p23.red[tid] = fmaxf(sh.p23.red[tid], sh.p23.red[tid+s]);
                __syncthreads();
            }
            float m = sh.p23.red[0];
            __syncthreads();
            float ex = (tid < P) ? __expf(e - m) : 0.f;
            sh.p23.red[tid] = ex;
            __syncthreads();
            for (int s = 256; s > 0; s >>= 1){
                if (tid < s) sh.p23.red[tid] += sh.p23.red[tid+s];
                __syncthreads();
            }
            float ssum = sh.p23.red[0];
            if (tid < P){
                float alpha = ex / ssum;
                sh.p23.aL[tid] = alpha;
                if (q == 0) p.outA[((size_t)(wj*T + t))*P + tid] = (t < lj) ? alpha : 0.f;
            }
            if (tid >= P && tid < 200) sh.p23.aL[tid] = 0.f;
            __syncthreads();

            // context quarter [q*512, q*512+512): wave w takes p = w, w+8, ...
            const short* ib = (const short*)p.img_s + (size_t)j*P*ENC + q*512 + l*8;
            float a8[8];
            #pragma unroll
            for (int z=0; z<8; ++z) a8[z] = 0.f;
            #pragma unroll 5
            for (int i = 0; i < 25; ++i){
                int pp2 = w + 8*i;
                bf16x8 v = *(const bf16x8*)(ib + (size_t)pp2*ENC);
                float al = sh.p23.aL[pp2];
                #pragma unroll
                for (int z=0; z<8; ++z) a8[z] += al * bfu(v[z]);
            }
            if (w < 4){
                #pragma unroll
                for (int z=0; z<8; ++z) sh.p23.ctxP[w][l*8+z] = a8[z];
            }
            __syncthreads();
            if (w >= 4){
                #pragma unroll
                for (int z=0; z<8; ++z) sh.p23.ctxP[w-4][l*8+z] += a8[z];
            }
            __syncthreads();
            {
                int d = tid;
                float ctx = sh.p23.ctxP[0][d] + sh.p23.ctxP[1][d] + sh.p23.ctxP[2][d] + sh.p23.ctxP[3][d];
                int eg = q*512 + d;
                float gate = sigm(p.D2[j*N2 + ATT + eg]);
                p.gc[j*ENC + eg] = __float2bfloat16(gate*ctx);
            }
        }
        gbar(p.barCnt, bk++);

        // ---- P4: gates GEMM (K-split waves, B from LDS) + LSTM + outputs ----
        {
            if (tid < 64){
                int o = p.idx[tid];
                sh.gem.tokL[tid] = p.sent[o*T + t];
                sh.gem.lensL[tid] = p.lens[o];
                sh.gem.wLs[tid] = p.rank[tid];
            }
            __syncthreads();
            int rt = w & 3, kh = w >> 2;
            int mrow = 16*rt + lm;
            int tok = sh.gem.tokL[mrow];
            const short* aEmb = (const short*)p.emb_bf + (size_t)tok*EMB + 8*lk;
            const short* aGc  = (const short*)p.gc + (size_t)mrow*ENC + 8*lk;
            const short* aH   = (const short*)hbIn + (size_t)mrow*HID + 8*lk;
            const bf16x8* BL = (const bf16x8*)WcatL;
            f32x4 acc = {0.f,0.f,0.f,0.f};
            if (kh == 0){
                #pragma unroll 8
                for (int kt = 0; kt < 16; ++kt){
                    bf16x8 a = *(const bf16x8*)(aEmb + kt*32);
                    acc = __builtin_amdgcn_mfma_f32_16x16x32_bf16(a, BL[kt*64 + l], acc, 0,0,0);
                }
                #pragma unroll 8
                for (int kt = 16; kt < 56; ++kt){
                    bf16x8 a = *(const bf16x8*)(aGc + (kt-16)*32);
                    acc = __builtin_amdgcn_mfma_f32_16x16x32_bf16(a, BL[kt*64 + l], acc, 0,0,0);
                }
            } else {
                #pragma unroll 8
                for (int kt = 56; kt < 80; ++kt){
                    bf16x8 a = *(const bf16x8*)(aGc + (kt-16)*32);
                    acc = __builtin_amdgcn_mfma_f32_16x16x32_bf16(a, BL[kt*64 + l], acc, 0,0,0);
                }
                #pragma unroll 8
                for (int kt = 80; kt < 112; ++kt){
                    bf16x8 a = *(const bf16x8*)(aH + (kt-80)*32);
                    acc = __builtin_amdgcn_mfma_f32_16x16x32_bf16(a, BL[kt*64 + l], acc, 0,0,0);
                }
            }
            #pragma unroll
            for (int r=0; r<4; ++r) sh.gem.Dp[kh][16*rt + 4*lk + r][lm] = acc[r];
            __syncthreads();
            if (tid < 256){
                int j2 = tid & 63, du = tid >> 6;
                int u = 4*b + du;
                float g4[4];
                #pragma unroll
                for (int g=0; g<4; ++g){
                    int nl = 4*du + g;
                    g4[g] = sh.gem.Dp[0][j2][nl] + sh.gem.Dp[1][j2][nl] + p.bsum[16*b + nl];
                }
                float ig = sigm(g4[0]), fg = sigm(g4[1]), gg = tanhf(g4[2]), og = sigm(g4[3]);
                float cOld = p.cW[j2*HID + u];
                float cNew = fg*cOld + ig*gg;
                float hNew = og*tanhf(cNew);
                bool active = (t < sh.gem.lensL[j2]);
                float hOld = hFIn[j2*HID + u];
                float hKeep = active ? hNew : hOld;
                hFOut[j2*HID + u] = hKeep;
                hbOut[j2*HID + u] = __float2bfloat16(hKeep);
                p.cW[j2*HID + u] = active ? cNew : cOld;
                p.outH[((size_t)sh.gem.wLs[j2]*T + t)*HID + u] = active ? hNew : 0.f;
            }
        }
        gbar(p.barCnt, bk++);
    }
}

extern "C" void kernel_launch(void* const* d_in, const int* in_sizes, int n_in,
                              void* d_out, int out_size, void* d_ws, size_t ws_size,
                              hipStream_t stream) {
    const float* img   = (const float*)d_in[0];
    const int*   sent  = (const int*)  d_in[1];
    const float* enc_h = (const float*)d_in[2];
    const float* enc_c = (const float*)d_in[3];
    const int*   lens  = (const int*)  d_in[4];
    const float* emb   = (const float*)d_in[5];
    const float* Wea   = (const float*)d_in[6];
    const float* bea   = (const float*)d_in[7];
    const float* Wda   = (const float*)d_in[8];
    const float* bda   = (const float*)d_in[9];
    const float* wfa   = (const float*)d_in[10];
    const float* bfa   = (const float*)d_in[11];
    const float* Wfb   = (const float*)d_in[12];
    const float* bfb   = (const float*)d_in[13];
    const float* Wih   = (const float*)d_in[14];
    const float* bih   = (const float*)d_in[15];
    const float* Whh   = (const float*)d_in[16];
    const float* bhh   = (const float*)d_in[17];

    float* outH = (float*)d_out;                       // [B,T,HID] f32
    float* outA = outH + (size_t)B*T*HID;              // [B,T,P]  f32

    char* wsb = (char*)d_ws;
    size_t off = 0;
    int* idxW  = (int*)(wsb + off); off += 256;
    int* rankW = (int*)(wsb + off); off += 256;
    unsigned* barCnt = (unsigned*)(wsb + off); off += 16384;   // 8 group counters (1KB apart) + top
    __hip_bfloat16* att1w = (__hip_bfloat16*)(wsb + off); off += (size_t)B*P*ATT*2;       // 12.85MB
    __hip_bfloat16* img_s = (__hip_bfloat16*)(wsb + off); off += (size_t)B*P*ENC*2;       // 51.38MB
    __hip_bfloat16* emb_bf= (__hip_bfloat16*)(wsb + off); off += (size_t)10000*EMB*2;     // 10.24MB
    __hip_bfloat16* Wfrag = (__hip_bfloat16*)(wsb + off); off += (size_t)4*HID*KTOT*2;    // 29.36MB
    __hip_bfloat16* W2    = (__hip_bfloat16*)(wsb + off); off += (size_t)N2*HID*2;        // 5.24MB
    __hip_bfloat16* Wea_bf= (__hip_bfloat16*)(wsb + off); off += (size_t)ATT*ENC*2;       // 2.10MB (prologue-only)
    float* bsum  = (float*)(wsb + off); off += 4*HID*4;
    float* bias2 = (float*)(wsb + off); off += N2*4;
    float* hA    = (float*)(wsb + off); off += B*HID*4;
    float* hB    = (float*)(wsb + off); off += B*HID*4;
    float* cWs   = (float*)(wsb + off); off += B*HID*4;
    __hip_bfloat16* hbfA = (__hip_bfloat16*)(wsb + off); off += B*HID*2;
    __hip_bfloat16* hbfB = (__hip_bfloat16*)(wsb + off); off += B*HID*2;
    float* D2    = (float*)(wsb + off); off += (size_t)B*N2*4;
    __hip_bfloat16* gcW  = (__hip_bfloat16*)(wsb + off); off += B*ENC*2;

    k_sort<<<1, 64, 0, stream>>>(lens, idxW, rankW, barCnt);
    k_init_hc<<<B, 256, 0, stream>>>(enc_h, enc_c, idxW, hA, cWs, hbfA);
    k_cvt_wcat<<<57344, 256, 0, stream>>>(Wih, Whh, Wfrag);
    k_bsum<<<16, 256, 0, stream>>>(bih, bhh, bsum);
    k_cvt_w2<<<N2, 256, 0, stream>>>(Wda, bda, Wfb, bfb, W2, bias2);
    k_cvt_emb<<<20000, 256, 0, stream>>>(emb, emb_bf);
    k_cvt_wea<<<ATT, 256, 0, stream>>>(Wea, Wea_bf);
    k_cvt_img<<<dim3(P*ENC/256, B), 256, 0, stream>>>(img, idxW, img_s);
    k_att1m<<<dim3((B*P)/64, ATT/64), 256, 0, stream>>>(img_s, Wea_bf, bea, att1w);

    SP sp;
    sp.att1w = att1w; sp.img_s = img_s; sp.emb_bf = emb_bf; sp.Wfrag = Wfrag; sp.W2 = W2;
    sp.bsum = bsum; sp.bias2 = bias2; sp.wfa = wfa; sp.bfa = bfa;
    sp.sent = sent; sp.idx = idxW; sp.rank = rankW; sp.lens = lens;
    sp.D2 = D2; sp.gc = gcW;
    sp.hF0 = hA; sp.hF1 = hB; sp.cW = cWs;
    sp.hb0 = hbfA; sp.hb1 = hbfB;
    sp.outH = outH; sp.outA = outA;
    sp.barCnt = barCnt;

    void* args[] = { &sp };
    hipLaunchCooperativeKernel(reinterpret_cast<void*>(k_scan), dim3(NBLK), dim3(NTHR),
                               args, 0, stream);
}